// Round 11
// baseline (1080.798 us; speedup 1.0000x reference)
//
#include <hip/hip_runtime.h>

// ---------------------------------------------------------------------------
// SSM (Mamba2-style) fused forward for MI355X.
// R11: cross-block overlap restored. gemm1 ring-2 dbuf (LDS 56KB -> 2
//      blocks/CU, launch_bounds(512,4)); gemm2 re-tiled 128x128/256thr
//      ring-2 (32KB, grid 512, 2+ blocks/CU). Simple tile body (R9 style):
//      stage(t+1) -> read frags(t) -> MFMA -> vmcnt(0) -> barrier.
//      Ring-2 legality: frag ds_reads of tile t complete before the wave
//      passes t's end barrier (lgkm waits gate the MFMAs), so t+1's stage
//      of the other buffer never races.
// ws layout (bytes): unchanged from R7-R10.
// ---------------------------------------------------------------------------

typedef short s16x8 __attribute__((ext_vector_type(8)));
typedef float f32x4 __attribute__((ext_vector_type(4)));

__device__ __forceinline__ float bf2f(ushort u) {
    return __builtin_bit_cast(float, (unsigned)u << 16);
}
__device__ __forceinline__ ushort f2bf(float f) {
    unsigned u = __builtin_bit_cast(unsigned, f);
    unsigned r = u + 0x7fffu + ((u >> 16) & 1u);
    return (ushort)(r >> 16);
}

__device__ __forceinline__ void gld16(const void* g, void* l) {
    __builtin_amdgcn_global_load_lds((__attribute__((address_space(1))) void*)g,
                                     (__attribute__((address_space(3))) void*)l, 16, 0, 0);
}

#define BARRIER() asm volatile("s_barrier" ::: "memory")

// ---------------- unified cast kernel ----------------
__global__ void cast_all_k(const float4* __restrict__ x, const float4* __restrict__ wout,
                           const float4* __restrict__ win, ushort* __restrict__ xb,
                           ushort* __restrict__ woutb, ushort* __restrict__ winb) {
    const long b = blockIdx.x, tid = threadIdx.x;
    if (b < 8192) {
        long i = b * 256 + tid;
        float4 v = x[i];
        ushort4 o = { f2bf(v.x), f2bf(v.y), f2bf(v.z), f2bf(v.w) };
        *(ushort4*)(xb + i * 4) = o;
    } else if (b < 16384) {
        long i = (b - 8192) * 256 + tid;
        float4 v = wout[i];
        ushort4 o = { f2bf(v.x), f2bf(v.y), f2bf(v.z), f2bf(v.w) };
        *(ushort4*)(woutb + i * 4) = o;
    } else {
        long i = (b - 16384) * 256 + tid;   // < 8832*2048/4
        ushort4 o;
        if (i < 4341760L) {                 // 8480*2048/4
            float4 v = win[i];
            o = { f2bf(v.x), f2bf(v.y), f2bf(v.z), f2bf(v.w) };
        } else {
            o = { 0, 0, 0, 0 };
        }
        *(ushort4*)(winb + i * 4) = o;
    }
}

// ---------------- GEMM1: 256x192 tile, BK=32, ring-2, 2 blocks/CU ---------
__global__ __launch_bounds__(512, 4) void gemm1_k(const ushort* __restrict__ A,
                                                  const ushort* __restrict__ Bm,
                                                  ushort* __restrict__ zbuf,
                                                  ushort* __restrict__ xbc,
                                                  ushort* __restrict__ dtr) {
    constexpr int K = 2048, NT = 64;
    __shared__ ushort lds[2 * 8192 + 2 * 6144];   // 56 KB
    const int tid = threadIdx.x, lane = tid & 63, wave = tid >> 6;
    const int wm = wave >> 2, wn = wave & 3;
    const int bid = blockIdx.x;
    const int xcd = bid & 7, w = bid >> 3;
    const int mt = xcd * 2 + (w & 1), nt = w >> 1;
    const long m0 = (long)mt * 256, n0 = (long)nt * 192;

    const int st_row = lane >> 2;
    const int st_gc = ((lane & 3) * 8) ^ (((lane >> 5) & 1) << 4);

    auto STAGE = [&](int buf, int kt) {
#pragma unroll
        for (int j = 0; j < 2; j++) {
            int sidx = wave + j * 8;
            gld16(A + (m0 + sidx * 16 + st_row) * K + kt + st_gc,
                  lds + buf * 8192 + sidx * 512 + lane * 8);
        }
#pragma unroll
        for (int j = 0; j < 2; j++) {
            int sidx = wave + j * 8;
            if (sidx < 12)
                gld16(Bm + (n0 + sidx * 16 + st_row) * K + kt + st_gc,
                      lds + 16384 + buf * 6144 + sidx * 512 + lane * 8);
        }
    };

    const int cfr = (lane >> 4) * 8;
    const int lr = lane & 15;
    auto LDFA = [&](int buf, int r) -> s16x8 {
        int off = buf * 8192 + ((r >> 4) << 9) + ((r & 15) << 5)
                + (cfr ^ (((r >> 3) & 1) << 4));
        return *(const s16x8*)(lds + off);
    };
    auto LDFB = [&](int buf, int r) -> s16x8 {
        int off = 16384 + buf * 6144 + ((r >> 4) << 9) + ((r & 15) << 5)
                + (cfr ^ (((r >> 3) & 1) << 4));
        return *(const s16x8*)(lds + off);
    };

    f32x4 zero = { 0.f, 0.f, 0.f, 0.f };
    f32x4 acc[8][3];
#pragma unroll
    for (int i = 0; i < 8; i++)
#pragma unroll
        for (int j = 0; j < 3; j++) acc[i][j] = zero;

    STAGE(0, 0);
    asm volatile("s_waitcnt vmcnt(0)" ::: "memory");
    BARRIER();

    for (int t = 0; t < NT; ++t) {
        const int cur = t & 1;
        if ((t + 1) < NT) STAGE((t + 1) & 1, (t + 1) * 32);

        s16x8 bfr[3], alo[4], ahi[4];
#pragma unroll
        for (int ni = 0; ni < 3; ni++) bfr[ni] = LDFB(cur, wn * 48 + ni * 16 + lr);
#pragma unroll
        for (int mi = 0; mi < 4; mi++) alo[mi] = LDFA(cur, wm * 128 + mi * 16 + lr);
#pragma unroll
        for (int mi = 0; mi < 4; mi++) ahi[mi] = LDFA(cur, wm * 128 + 64 + mi * 16 + lr);

        __builtin_amdgcn_s_setprio(1);
#pragma unroll
        for (int mi = 0; mi < 4; mi++)
#pragma unroll
            for (int ni = 0; ni < 3; ni++)
                acc[mi][ni] = __builtin_amdgcn_mfma_f32_16x16x32_bf16(alo[mi], bfr[ni], acc[mi][ni], 0, 0, 0);
#pragma unroll
        for (int mi = 0; mi < 4; mi++)
#pragma unroll
            for (int ni = 0; ni < 3; ni++)
                acc[mi + 4][ni] = __builtin_amdgcn_mfma_f32_16x16x32_bf16(ahi[mi], bfr[ni], acc[mi + 4][ni], 0, 0, 0);
        __builtin_amdgcn_s_setprio(0);

        asm volatile("s_waitcnt vmcnt(0)" ::: "memory");
        BARRIER();
    }

    const int lr4 = (lane >> 4) * 4;
#pragma unroll
    for (int mi = 0; mi < 8; mi++) {
#pragma unroll
        for (int ni = 0; ni < 3; ni++) {
            const long col = n0 + wn * 48 + ni * 16 + lr;
            ushort* dst;
            long stride;
            if (col < 4096)      { dst = zbuf + col;         stride = 4096; }
            else if (col < 8448) { dst = xbc + (col - 4096); stride = 4352; }
            else if (col < 8480) { dst = dtr + (col - 8448); stride = 32;   }
            else continue;
            const long row0 = m0 + wm * 128 + mi * 16 + lr4;
#pragma unroll
            for (int r = 0; r < 4; r++) dst[(row0 + r) * stride] = f2bf(acc[mi][ni][r]);
        }
    }
}

// ---------------- GEMM2: 128x128 tile, BK=32, ring-2, grid 512 ------------
__global__ __launch_bounds__(256, 4) void gemm2_k(const ushort* __restrict__ A,
                                                  const ushort* __restrict__ Bm,
                                                  float* __restrict__ Cout) {
    constexpr int K = 4096, NT = 128;
    __shared__ ushort lds[2 * 4096 + 2 * 4096];   // 32 KB
    const int tid = threadIdx.x, lane = tid & 63, wave = tid >> 6;
    const int wm = wave >> 1, wn = wave & 1;
    const int bid = blockIdx.x;                    // 512 = 8 x (4 mt x 16 nt)
    const int xcd = bid & 7, w = bid >> 3;
    const int mt = xcd * 4 + (w & 3), nt = w >> 2;
    const long m0 = (long)mt * 128, n0 = (long)nt * 128;

    const int st_row = lane >> 2;
    const int st_gc = ((lane & 3) * 8) ^ (((lane >> 5) & 1) << 4);

    auto STAGE = [&](int buf, int kt) {
#pragma unroll
        for (int j = 0; j < 2; j++) {
            int sidx = wave + j * 4;               // 8 subtiles (128 rows)
            gld16(A + (m0 + sidx * 16 + st_row) * K + kt + st_gc,
                  lds + buf * 4096 + sidx * 512 + lane * 8);
        }
#pragma unroll
        for (int j = 0; j < 2; j++) {
            int sidx = wave + j * 4;
            gld16(Bm + (n0 + sidx * 16 + st_row) * K + kt + st_gc,
                  lds + 8192 + buf * 4096 + sidx * 512 + lane * 8);
        }
    };

    const int cfr = (lane >> 4) * 8;
    const int lr = lane & 15;
    auto LDFA = [&](int buf, int r) -> s16x8 {
        int off = buf * 4096 + ((r >> 4) << 9) + ((r & 15) << 5)
                + (cfr ^ (((r >> 3) & 1) << 4));
        return *(const s16x8*)(lds + off);
    };
    auto LDFB = [&](int buf, int r) -> s16x8 {
        int off = 8192 + buf * 4096 + ((r >> 4) << 9) + ((r & 15) << 5)
                + (cfr ^ (((r >> 3) & 1) << 4));
        return *(const s16x8*)(lds + off);
    };

    f32x4 zero = { 0.f, 0.f, 0.f, 0.f };
    f32x4 acc[4][4];
#pragma unroll
    for (int i = 0; i < 4; i++)
#pragma unroll
        for (int j = 0; j < 4; j++) acc[i][j] = zero;

    STAGE(0, 0);
    asm volatile("s_waitcnt vmcnt(0)" ::: "memory");
    BARRIER();

    for (int t = 0; t < NT; ++t) {
        const int cur = t & 1;
        if ((t + 1) < NT) STAGE((t + 1) & 1, (t + 1) * 32);

        s16x8 af[4], bf[4];
#pragma unroll
        for (int mi = 0; mi < 4; mi++) af[mi] = LDFA(cur, wm * 64 + mi * 16 + lr);
#pragma unroll
        for (int ni = 0; ni < 4; ni++) bf[ni] = LDFB(cur, wn * 64 + ni * 16 + lr);

        __builtin_amdgcn_s_setprio(1);
#pragma unroll
        for (int mi = 0; mi < 4; mi++)
#pragma unroll
            for (int ni = 0; ni < 4; ni++)
                acc[mi][ni] = __builtin_amdgcn_mfma_f32_16x16x32_bf16(af[mi], bf[ni], acc[mi][ni], 0, 0, 0);
        __builtin_amdgcn_s_setprio(0);

        asm volatile("s_waitcnt vmcnt(0)" ::: "memory");
        BARRIER();
    }

    const long crow = m0 + wm * 64 + ((lane >> 4) << 2);
    const long ccol = n0 + wn * 64 + (lane & 15);
#pragma unroll
    for (int mi = 0; mi < 4; mi++)
#pragma unroll
        for (int ni = 0; ni < 4; ni++)
#pragma unroll
            for (int r = 0; r < 4; r++)
                Cout[(crow + mi * 16 + r) * 2048 + ccol + ni * 16] = acc[mi][ni][r];
}

// ---------------- fused causal conv (K=4) + SiLU + transpose ----------------
__global__ __launch_bounds__(256) void convx_k(const ushort* __restrict__ xbc,
                                               const float* __restrict__ w,
                                               const float* __restrict__ bias,
                                               ushort* __restrict__ xbcc,
                                               ushort* __restrict__ xT,
                                               ushort* __restrict__ Bt) {
    __shared__ ushort xin[35][136];
    __shared__ ushort yL[32][132];
    const int stile = blockIdx.x, slot = blockIdx.y, bc = blockIdx.z;
    const int tid = threadIdx.x;
    const int cc = bc & 7;
    const long tbase = (long)bc * 256 + stile * 32;
    const int c0 = slot * 128;
    const bool head = (cc == 0 && stile == 0);

#pragma unroll
    for (int i = 0; i < 3; i++) {
        int u = tid + i * 256;
        if (u < 560) {
            int r = u >> 4, seg = u & 15;
            s16x8 v;
            if (head && r < 3) {
#pragma unroll
                for (int j = 0; j < 8; j++) v[j] = 0;
            } else {
                v = *(const s16x8*)&xbc[(tbase - 3 + r) * 4352 + c0 + seg * 8];
            }
            *(s16x8*)&xin[r][seg * 8] = v;
        }
    }
    __syncthreads();

    const int s_loc = tid >> 3, p0 = (tid & 7) * 16;
    ushort yo[16];
#pragma unroll
    for (int j = 0; j < 16; j++) {
        int c = p0 + j;
        float a = bias[c0 + c];
#pragma unroll
        for (int k = 0; k < 4; k++)
            a += bf2f(xin[s_loc + k][c]) * w[(c0 + c) * 4 + k];
        float yv = a / (1.f + __expf(-a));
        ushort ub = f2bf(yv);
        yo[j] = ub;
        yL[s_loc][c] = ub;
    }
    *(s16x8*)&xbcc[(tbase + s_loc) * 4352 + c0 + p0] = *(const s16x8*)&yo[0];
    *(s16x8*)&xbcc[(tbase + s_loc) * 4352 + c0 + p0 + 8] = *(const s16x8*)&yo[8];
    __syncthreads();

    if (slot < 33) {
        const int p = tid >> 1, s0 = (tid & 1) * 16;
        ushort o[16];
#pragma unroll
        for (int j = 0; j < 16; j++) o[j] = yL[s0 + j][p];
        ushort* dst = (slot < 32)
            ? (xT + ((long)(bc * 32 + slot) * 128 + p) * 256 + stile * 32 + s0)
            : (Bt + ((long)bc * 128 + p) * 256 + stile * 32 + s0);
        *(s16x8*)&dst[0] = *(const s16x8*)&o[0];
        *(s16x8*)&dst[8] = *(const s16x8*)&o[8];
    }
}

// ---------------- dt softplus/clip + per-chunk cumsum ----------------
__global__ void prep_k(const ushort* __restrict__ dtr, const float* __restrict__ dt_bias,
                       const float* __restrict__ A_log, float* __restrict__ dtp,
                       float* __restrict__ dacs) {
    const int bx = blockIdx.x;
    const int h = bx & 31, cc = (bx >> 5) & 7, bi = bx >> 8;
    const int lane = threadIdx.x;
    const float A = -__expf(A_log[h]);
    const float bsh = dt_bias[h];
    float v[4], cs[4];
    float run = 0.f;
#pragma unroll
    for (int j = 0; j < 4; j++) {
        int pos = cc * 256 + lane * 4 + j;
        float raw = bf2f(dtr[((long)(bi * 2048 + pos)) * 32 + h]) + bsh;
        float sp = (raw > 20.f) ? raw : log1pf(__expf(raw));
        float d = fminf(fmaxf(sp, 0.001f), 0.1f);
        v[j] = d;
        run += d * A;
        cs[j] = run;
    }
    float tot = run, pre = run;
    for (int off = 1; off < 64; off <<= 1) {
        float u = __shfl_up(pre, off, 64);
        if (lane >= off) pre += u;
    }
    float excl = pre - tot;
    const long base = ((long)(bi * 32 + h)) * 2048 + cc * 256 + lane * 4;
#pragma unroll
    for (int j = 0; j < 4; j++) { dtp[base + j] = v[j]; dacs[base + j] = excl + cs[j]; }
}

// ---------------- CB = C.B^T per chunk via MFMA ----------------
__global__ __launch_bounds__(256) void cb_mfma_k(const ushort* __restrict__ xbcc,
                                                 float* __restrict__ CB) {
    const int bid = blockIdx.x;
    const int sq = bid & 1, lq = (bid >> 1) & 1, bc = bid >> 2;
    const int tid = threadIdx.x, lane = tid & 63, wave = tid >> 6;
    const int wm = wave >> 1, wn = wave & 1;
    const long tbase = (long)bc * 256;

    f32x4 zero = { 0.f, 0.f, 0.f, 0.f };
    f32x4 acc[4][4];
#pragma unroll
    for (int i = 0; i < 4; i++)
#pragma unroll
        for (int j = 0; j < 4; j++) acc[i][j] = zero;

    for (int kst = 0; kst < 4; ++kst) {
        const int koff = kst * 32 + (lane >> 4) * 8;
        s16x8 a[4], b[4];
#pragma unroll
        for (int mi = 0; mi < 4; mi++) {
            int l = lq * 128 + wm * 64 + mi * 16 + (lane & 15);
            a[mi] = *(const s16x8*)&xbcc[(tbase + l) * 4352 + 4224 + koff];
        }
#pragma unroll
        for (int ni = 0; ni < 4; ni++) {
            int s = sq * 128 + wn * 64 + ni * 16 + (lane & 15);
            b[ni] = *(const s16x8*)&xbcc[(tbase + s) * 4352 + 4096 + koff];
        }
#pragma unroll
        for (int mi = 0; mi < 4; mi++)
#pragma unroll
            for (int ni = 0; ni < 4; ni++)
                acc[mi][ni] = __builtin_amdgcn_mfma_f32_16x16x32_bf16(a[mi], b[ni], acc[mi][ni], 0, 0, 0);
    }

    float* out = CB + (long)bc * 65536;
#pragma unroll
    for (int mi = 0; mi < 4; mi++)
#pragma unroll
        for (int ni = 0; ni < 4; ni++)
#pragma unroll
            for (int r = 0; r < 4; r++) {
                int l = lq * 128 + wm * 64 + mi * 16 + (lane >> 4) * 4 + r;
                int s = sq * 128 + wn * 64 + ni * 16 + (lane & 15);
                out[(long)l * 256 + s] = acc[mi][ni][r];
            }
}

// ---------------- fused intra+inter scan via MFMA (single yf write) --------
__global__ __launch_bounds__(256) void scan_mfma_k(const ushort* __restrict__ xT,
                                                   const float* __restrict__ CB,
                                                   const float* __restrict__ dtp,
                                                   const float* __restrict__ dacs,
                                                   const ushort* __restrict__ xbcc,
                                                   const float* __restrict__ st,
                                                   float* __restrict__ yf) {
    const int bx = blockIdx.x;
    const int ltile = bx & 1, h = (bx >> 1) & 31, cc = (bx >> 6) & 7, bi = bx >> 9;
    const int tid = threadIdx.x, lane = tid & 63, wave = tid >> 6;
    const int wm = wave >> 1, wn = wave & 1;

    __shared__ float dA_s[256];
    __shared__ float F_s[256];

    const long dbase = ((long)(bi * 32 + h)) * 2048 + cc * 256;
    {
        float a = dacs[dbase + tid];
        float r = dacs[dbase + (tid | 31)];
        dA_s[tid] = a;
        F_s[tid] = __expf(r - a) * dtp[dbase + tid];
    }
    __syncthreads();

    int lch[4];
    float dAl[4];
#pragma unroll
    for (int mi = 0; mi < 4; mi++) {
        lch[mi] = ltile * 128 + wm * 64 + mi * 16 + (lane & 15);
        dAl[mi] = dA_s[lch[mi]];
    }

    f32x4 zero = { 0.f, 0.f, 0.f, 0.f };
    f32x4 acc[4][4];
#pragma unroll
    for (int i = 0; i < 4; i++)
#pragma unroll
        for (int j = 0; j < 4; j++) acc[i][j] = zero;

    const long tbase = (long)bi * 2048 + cc * 256;
    const long cbbase = ((long)(bi * 8 + cc)) * 65536;
    const ushort* xrow = xT + (((long)(bi * 8 + cc) * 32 + h) * 128) * 256;
    const int nsb = ltile * 4 + 4;

    for (int sb = 0; sb < nsb; ++sb) {
        const int soff = sb * 32 + (lane >> 4) * 8;
        s16x8 bf[4];
#pragma unroll
        for (int ni = 0; ni < 4; ni++) {
            int p = wn * 64 + ni * 16 + (lane & 15);
            bf[ni] = *(const s16x8*)&xrow[(long)p * 256 + soff];
        }
        const float Rsb = dA_s[sb * 32 + 31];
        const int s0 = soff;
#pragma unroll
        for (int mi = 0; mi < 4; mi++) {
            const int lb = lch[mi] >> 5;
            if (sb > lb) continue;
            const float* cbrow = CB + cbbase + (long)lch[mi] * 256 + s0;
            float4 c0 = *(const float4*)cbrow;
            float4 c1 = *(const float4*)(cbrow + 4);
            float E = __expf(dAl[mi] - Rsb);
            float m[8];
            m[0] = c0.x * E * F_s[s0 + 0]; m[1] = c0.y * E * F_s[s0 + 1];
            m[2] = c0.z * E * F_s[s0 + 2]; m[3] = c0.w * E * F_s[s0 + 3];
            m[4] = c1.x * E * F_s[s0 + 4]; m[5] = c1.y * E * F_s[s0 + 5];
            m[6] = c1.z * E * F_s[s0 + 6]; m[7] = c1.w * E * F_s[s0 + 7];
            if (sb == lb) {
#pragma unroll
                for (int j = 0; j < 8; j++)
                    if (s0 + j > lch[mi]) m[j] = 0.f;
            }
            s16x8 a;
#pragma unroll
            for (int j = 0; j < 8; j++) a[j] = (short)f2bf(m[j]);
#pragma unroll
            for (int ni = 0; ni < 4; ni++)
                acc[mi][ni] = __builtin_amdgcn_mfma_f32_16x16x32_bf16(a, bf[ni], acc[mi][ni], 0, 0, 0);
        }
    }

    const float* sbase = st + (((long)(bi * 8 + cc) * 32 + h) * 128) * 128;
    float eAr[4];
#pragma unroll
    for (int mi = 0; mi < 4; mi++) eAr[mi] = __expf(dAl[mi]);
    for (int kk = 0; kk < 4; ++kk) {
        const int koff = kk * 32 + (lane >> 4) * 8;
        s16x8 a[4], b[4];
#pragma unroll
        for (int mi = 0; mi < 4; mi++) {
            s16x8 raw = *(const s16x8*)&xbcc[(tbase + lch[mi]) * 4352 + 4224 + koff];
#pragma unroll
            for (int j = 0; j < 8; j++)
                a[mi][j] = (short)f2bf(bf2f((ushort)raw[j]) * eAr[mi]);
        }
#pragma unroll
        for (int ni = 0; ni < 4; ni++) {
            int p = wn * 64 + ni * 16 + (lane & 15);
            const float* pr = sbase + (long)p * 128 + koff;
            float4 v0 = *(const float4*)pr;
            float4 v1 = *(const float4*)(pr + 4);
            b[ni][0] = (short)f2bf(v0.x); b[ni][1] = (short)f2bf(v0.y);
            b[ni][2] = (short)f2bf(v0.z); b[ni][3] = (short)f2bf(v0.w);
            b[ni][4] = (short)f2bf(v1.x); b[ni][5] = (short)f2bf(v1.y);
            b[ni][6] = (short)f2bf(v1.z); b[ni][7] = (short)f2bf(v1.w);
        }
#pragma unroll
        for (int mi = 0; mi < 4; mi++)
#pragma unroll
            for (int ni = 0; ni < 4; ni++)
                acc[mi][ni] = __builtin_amdgcn_mfma_f32_16x16x32_bf16(a[mi], b[ni], acc[mi][ni], 0, 0, 0);
    }

    const long crow = tbase + ltile * 128 + wm * 64 + ((lane >> 4) << 2);
    const int ccol = h * 128 + wn * 64 + (lane & 15);
#pragma unroll
    for (int mi = 0; mi < 4; mi++)
#pragma unroll
        for (int ni = 0; ni < 4; ni++)
#pragma unroll
            for (int r = 0; r < 4; r++)
                yf[(crow + mi * 16 + r) * 4096 + ccol + ni * 16] = acc[mi][ni][r];
}

// ---------------- per-chunk end states via MFMA ----------------
__global__ __launch_bounds__(256) void states_mfma_k(const ushort* __restrict__ xT,
                                                     const ushort* __restrict__ Bt,
                                                     const float* __restrict__ dtp,
                                                     const float* __restrict__ dacs,
                                                     float* __restrict__ states) {
    const int bx = blockIdx.x;
    const int h = bx & 31, cc = (bx >> 5) & 7, bi = bx >> 8;
    const int bc = bi * 8 + cc;
    const int tid = threadIdx.x, lane = tid & 63, wave = tid >> 6;
    const int wm = wave >> 1, wn = wave & 1;
    __shared__ float wl[256];
    const long dbase = ((long)(bi * 32 + h)) * 2048 + cc * 256;
    {
        float last = dacs[dbase + 255];
        wl[tid] = __expf(last - dacs[dbase + tid]) * dtp[dbase + tid];
    }
    __syncthreads();

    f32x4 zero = { 0.f, 0.f, 0.f, 0.f };
    f32x4 acc[4][4];
#pragma unroll
    for (int i = 0; i < 4; i++)
#pragma unroll
        for (int j = 0; j < 4; j++) acc[i][j] = zero;

    const ushort* xrow = xT + (((long)bc * 32 + h) * 128) * 256;
    const ushort* brow = Bt + ((long)bc * 128) * 256;

    for (int sb = 0; sb < 8; ++sb) {
        const int soff = sb * 32 + (lane >> 4) * 8;
        s16x8 a[4], b[4];
#pragma unroll
        for (int mi = 0; mi < 4; mi++) {
            int p = wm * 64 + mi * 16 + (lane & 15);
            s16x8 raw = *(const s16x8*)&xrow[(long)p * 256 + soff];
#pragma unroll
            for (int j = 0; j < 8; j++)
                a[mi][j] = (short)f2bf(bf2f((ushort)raw[j]) * wl[soff + j]);
        }
#pragma unroll
        for (int ni = 0; ni < 4; ni++) {
            int n = wn * 64 + ni * 16 + (lane & 15);
            b[ni] = *(const s16x8*)&brow[(long)n * 256 + soff];
        }
#pragma unroll
        for (int mi = 0; mi < 4; mi++)
#pragma unroll
            for (int ni = 0; ni < 4; ni++)
                acc[mi][ni] = __builtin_amdgcn_mfma_f32_16x16x32_bf16(a[mi], b[ni], acc[mi][ni], 0, 0, 0);
    }

    float* out = states + (((long)bc * 32 + h) * 128) * 128;
#pragma unroll
    for (int mi = 0; mi < 4; mi++)
#pragma unroll
        for (int ni = 0; ni < 4; ni++)
#pragma unroll
            for (int r = 0; r < 4; r++) {
                int p = wm * 64 + mi * 16 + (lane >> 4) * 4 + r;
                int n = wn * 64 + ni * 16 + (lane & 15);
                out[(long)p * 128 + n] = acc[mi][ni][r];
            }
}

// ---------------- chunk recurrence: states -> prev_states (in place) ----------------
__global__ void rec_k(float* __restrict__ states, const float* __restrict__ dacs) {
    const int i = blockIdx.x * 256 + threadIdx.x;
    const int n = i & 127, p = (i >> 7) & 127, h = (i >> 14) & 31, bi = i >> 19;
    const long dbase = ((long)(bi * 32 + h)) * 2048;
    float run = 0.f;
    for (int cc = 0; cc < 8; cc++) {
        const long off = ((((long)(bi * 8 + cc)) * 32 + h) * 128 + p) * 128 + n;
        float st = states[off];
        states[off] = run;
        float dec = dacs[dbase + cc * 256 + 255];
        run = run * __expf(dec) + st;
    }
}

// ---------------- gate (silu(z)) + D*x + RMSNorm -> bf16 ----------------
__global__ __launch_bounds__(256) void gate_rms_k(const float* __restrict__ y, const ushort* __restrict__ zbuf,
                                                  const ushort* __restrict__ xbcc, const float* __restrict__ Dv,
                                                  const float* __restrict__ norm_w, ushort* __restrict__ yb) {
    const int t = blockIdx.x, tid = threadIdx.x;
    const float* yr = &y[(long)t * 4096];
    const ushort* zr = &zbuf[(long)t * 4096];
    const ushort* xr = &xbcc[(long)t * 4352];
    float g[16];
    float ss = 0.f;
#pragma unroll
    for (int j = 0; j < 16; j++) {
        int i = j * 256 + tid;
        float z = bf2f(zr[i]);
        float yv = yr[i] + Dv[i >> 7] * bf2f(xr[i]);
        float gv = yv * (z / (1.f + __expf(-z)));
        g[j] = gv;
        ss += gv * gv;
    }
#pragma unroll
    for (int off = 32; off > 0; off >>= 1) ss += __shfl_xor(ss, off, 64);
    __shared__ float red[4];
    if ((tid & 63) == 0) red[tid >> 6] = ss;
    __syncthreads();
    float tot = red[0] + red[1] + red[2] + red[3];
    float sc = rsqrtf(tot * (1.f / 4096.f) + 1e-6f);
#pragma unroll
    for (int j = 0; j < 16; j++) {
        int i = j * 256 + tid;
        yb[(long)t * 4096 + i] = f2bf(g[j] * sc * norm_w[i]);
    }
}

// ---------------------------------------------------------------------------
extern "C" void kernel_launch(void* const* d_in, const int* in_sizes, int n_in,
                              void* d_out, int out_size, void* d_ws, size_t ws_size,
                              hipStream_t stream) {
    const float* x       = (const float*)d_in[0];
    const float* W_in    = (const float*)d_in[1];
    const float* conv_w  = (const float*)d_in[2];
    const float* conv_b  = (const float*)d_in[3];
    const float* dt_bias = (const float*)d_in[4];
    const float* A_log   = (const float*)d_in[5];
    const float* Dv      = (const float*)d_in[6];
    const float* norm_w  = (const float*)d_in[7];
    const float* W_out   = (const float*)d_in[8];

    char* w8 = (char*)d_ws;
    ushort* xb    = (ushort*)(w8 + 0L);
    ushort* xT    = (ushort*)(w8 + 0L);            // alias (xb dead after GEMM1)
    ushort* yb    = (ushort*)(w8 + 0L);            // alias (xT dead before gate)
    ushort* woutb = (ushort*)(w8 + 33554432L);
    ushort* Bt    = (ushort*)(w8 + 50331648L);
    ushort* zbuf  = (ushort*)(w8 + 52428800L);
    ushort* xbc   = (ushort*)(w8 + 85983232L);
    ushort* dtr   = (ushort*)(w8 + 121634816L);
    ushort* xbcc  = (ushort*)(w8 + 121896960L);
    float*  dtp   = (float*)(w8 + 157548544L);
    float*  dacs  = (float*)(w8 + 158072832L);
    float*  cb    = (float*)(w8 + 158597120L);
    float*  yf    = (float*)(w8 + 162791424L);
    ushort* winb  = (ushort*)(w8 + 162791424L);    // alias (dead before yf written)
    float*  st    = (float*)(w8 + 229900288L);

    cast_all_k<<<34048, 256, 0, stream>>>((const float4*)x, (const float4*)W_out,
                                          (const float4*)W_in, xb, woutb, winb);
    gemm1_k<<<736, 512, 0, stream>>>(xb, winb, zbuf, xbc, dtr);
    convx_k<<<dim3(8, 34, 16), 256, 0, stream>>>(xbc, conv_w, conv_b, xbcc, xT, Bt);
    prep_k<<<512, 64, 0, stream>>>(dtr, dt_bias, A_log, dtp, dacs);
    cb_mfma_k<<<64, 256, 0, stream>>>(xbcc, cb);
    states_mfma_k<<<512, 256, 0, stream>>>(xT, Bt, dtp, dacs, st);
    rec_k<<<4096, 256, 0, stream>>>(st, dacs);
    scan_mfma_k<<<1024, 256, 0, stream>>>(xT, cb, dtp, dacs, xbcc, st, yf);
    gate_rms_k<<<4096, 256, 0, stream>>>(yf, zbuf, xbcc, Dv, norm_w, yb);
    gemm2_k<<<512, 256, 0, stream>>>(yb, woutb, (float*)d_out);
}

// Round 12
// 473.871 us; speedup vs baseline: 2.2808x; 2.2808x over previous
//
#include <hip/hip_runtime.h>

// ---------------------------------------------------------------------------
// SSM (Mamba2-style) fused forward for MI355X.
// R12: R11 with the VGPR-spill fixed: launch_bounds min-waves clamp removed
//      (R11's (512,4) forced VGPR=64 < acc's 96 -> scratch spill, 1.34GB
//      writes). gemm1 ring-2 56KB (2 blocks/CU via LDS, compiler ~90 VGPR);
//      gemm2 128x128 ring-2 32KB (4 blocks/CU via VGPR).
// ws layout (bytes): unchanged from R7-R11.
// ---------------------------------------------------------------------------

typedef short s16x8 __attribute__((ext_vector_type(8)));
typedef float f32x4 __attribute__((ext_vector_type(4)));

__device__ __forceinline__ float bf2f(ushort u) {
    return __builtin_bit_cast(float, (unsigned)u << 16);
}
__device__ __forceinline__ ushort f2bf(float f) {
    unsigned u = __builtin_bit_cast(unsigned, f);
    unsigned r = u + 0x7fffu + ((u >> 16) & 1u);
    return (ushort)(r >> 16);
}

__device__ __forceinline__ void gld16(const void* g, void* l) {
    __builtin_amdgcn_global_load_lds((__attribute__((address_space(1))) void*)g,
                                     (__attribute__((address_space(3))) void*)l, 16, 0, 0);
}

#define BARRIER() asm volatile("s_barrier" ::: "memory")

// ---------------- unified cast kernel ----------------
__global__ void cast_all_k(const float4* __restrict__ x, const float4* __restrict__ wout,
                           const float4* __restrict__ win, ushort* __restrict__ xb,
                           ushort* __restrict__ woutb, ushort* __restrict__ winb) {
    const long b = blockIdx.x, tid = threadIdx.x;
    if (b < 8192) {
        long i = b * 256 + tid;
        float4 v = x[i];
        ushort4 o = { f2bf(v.x), f2bf(v.y), f2bf(v.z), f2bf(v.w) };
        *(ushort4*)(xb + i * 4) = o;
    } else if (b < 16384) {
        long i = (b - 8192) * 256 + tid;
        float4 v = wout[i];
        ushort4 o = { f2bf(v.x), f2bf(v.y), f2bf(v.z), f2bf(v.w) };
        *(ushort4*)(woutb + i * 4) = o;
    } else {
        long i = (b - 16384) * 256 + tid;   // < 8832*2048/4
        ushort4 o;
        if (i < 4341760L) {                 // 8480*2048/4
            float4 v = win[i];
            o = { f2bf(v.x), f2bf(v.y), f2bf(v.z), f2bf(v.w) };
        } else {
            o = { 0, 0, 0, 0 };
        }
        *(ushort4*)(winb + i * 4) = o;
    }
}

// ---------------- GEMM1: 256x192 tile, BK=32, ring-2, 2 blocks/CU ---------
__global__ __launch_bounds__(512) void gemm1_k(const ushort* __restrict__ A,
                                               const ushort* __restrict__ Bm,
                                               ushort* __restrict__ zbuf,
                                               ushort* __restrict__ xbc,
                                               ushort* __restrict__ dtr) {
    constexpr int K = 2048, NT = 64;
    __shared__ ushort lds[2 * 8192 + 2 * 6144];   // 56 KB
    const int tid = threadIdx.x, lane = tid & 63, wave = tid >> 6;
    const int wm = wave >> 2, wn = wave & 3;
    const int bid = blockIdx.x;
    const int xcd = bid & 7, w = bid >> 3;
    const int mt = xcd * 2 + (w & 1), nt = w >> 1;
    const long m0 = (long)mt * 256, n0 = (long)nt * 192;

    const int st_row = lane >> 2;
    const int st_gc = ((lane & 3) * 8) ^ (((lane >> 5) & 1) << 4);

    auto STAGE = [&](int buf, int kt) {
#pragma unroll
        for (int j = 0; j < 2; j++) {
            int sidx = wave + j * 8;
            gld16(A + (m0 + sidx * 16 + st_row) * K + kt + st_gc,
                  lds + buf * 8192 + sidx * 512 + lane * 8);
        }
#pragma unroll
        for (int j = 0; j < 2; j++) {
            int sidx = wave + j * 8;
            if (sidx < 12)
                gld16(Bm + (n0 + sidx * 16 + st_row) * K + kt + st_gc,
                      lds + 16384 + buf * 6144 + sidx * 512 + lane * 8);
        }
    };

    const int cfr = (lane >> 4) * 8;
    const int lr = lane & 15;
    auto LDFA = [&](int buf, int r) -> s16x8 {
        int off = buf * 8192 + ((r >> 4) << 9) + ((r & 15) << 5)
                + (cfr ^ (((r >> 3) & 1) << 4));
        return *(const s16x8*)(lds + off);
    };
    auto LDFB = [&](int buf, int r) -> s16x8 {
        int off = 16384 + buf * 6144 + ((r >> 4) << 9) + ((r & 15) << 5)
                + (cfr ^ (((r >> 3) & 1) << 4));
        return *(const s16x8*)(lds + off);
    };

    f32x4 zero = { 0.f, 0.f, 0.f, 0.f };
    f32x4 acc[8][3];
#pragma unroll
    for (int i = 0; i < 8; i++)
#pragma unroll
        for (int j = 0; j < 3; j++) acc[i][j] = zero;

    STAGE(0, 0);
    asm volatile("s_waitcnt vmcnt(0)" ::: "memory");
    BARRIER();

    for (int t = 0; t < NT; ++t) {
        const int cur = t & 1;
        if ((t + 1) < NT) STAGE((t + 1) & 1, (t + 1) * 32);

        s16x8 bfr[3], alo[4], ahi[4];
#pragma unroll
        for (int ni = 0; ni < 3; ni++) bfr[ni] = LDFB(cur, wn * 48 + ni * 16 + lr);
#pragma unroll
        for (int mi = 0; mi < 4; mi++) alo[mi] = LDFA(cur, wm * 128 + mi * 16 + lr);
#pragma unroll
        for (int mi = 0; mi < 4; mi++) ahi[mi] = LDFA(cur, wm * 128 + 64 + mi * 16 + lr);

        __builtin_amdgcn_s_setprio(1);
#pragma unroll
        for (int mi = 0; mi < 4; mi++)
#pragma unroll
            for (int ni = 0; ni < 3; ni++)
                acc[mi][ni] = __builtin_amdgcn_mfma_f32_16x16x32_bf16(alo[mi], bfr[ni], acc[mi][ni], 0, 0, 0);
#pragma unroll
        for (int mi = 0; mi < 4; mi++)
#pragma unroll
            for (int ni = 0; ni < 3; ni++)
                acc[mi + 4][ni] = __builtin_amdgcn_mfma_f32_16x16x32_bf16(ahi[mi], bfr[ni], acc[mi + 4][ni], 0, 0, 0);
        __builtin_amdgcn_s_setprio(0);

        asm volatile("s_waitcnt vmcnt(0)" ::: "memory");
        BARRIER();
    }

    const int lr4 = (lane >> 4) * 4;
#pragma unroll
    for (int mi = 0; mi < 8; mi++) {
#pragma unroll
        for (int ni = 0; ni < 3; ni++) {
            const long col = n0 + wn * 48 + ni * 16 + lr;
            ushort* dst;
            long stride;
            if (col < 4096)      { dst = zbuf + col;         stride = 4096; }
            else if (col < 8448) { dst = xbc + (col - 4096); stride = 4352; }
            else if (col < 8480) { dst = dtr + (col - 8448); stride = 32;   }
            else continue;
            const long row0 = m0 + wm * 128 + mi * 16 + lr4;
#pragma unroll
            for (int r = 0; r < 4; r++) dst[(row0 + r) * stride] = f2bf(acc[mi][ni][r]);
        }
    }
}

// ---------------- GEMM2: 128x128 tile, BK=32, ring-2, grid 512 ------------
__global__ __launch_bounds__(256) void gemm2_k(const ushort* __restrict__ A,
                                               const ushort* __restrict__ Bm,
                                               float* __restrict__ Cout) {
    constexpr int K = 4096, NT = 128;
    __shared__ ushort lds[2 * 4096 + 2 * 4096];   // 32 KB
    const int tid = threadIdx.x, lane = tid & 63, wave = tid >> 6;
    const int wm = wave >> 1, wn = wave & 1;
    const int bid = blockIdx.x;                    // 512 = 8 x (4 mt x 16 nt)
    const int xcd = bid & 7, w = bid >> 3;
    const int mt = xcd * 4 + (w & 3), nt = w >> 2;
    const long m0 = (long)mt * 128, n0 = (long)nt * 128;

    const int st_row = lane >> 2;
    const int st_gc = ((lane & 3) * 8) ^ (((lane >> 5) & 1) << 4);

    auto STAGE = [&](int buf, int kt) {
#pragma unroll
        for (int j = 0; j < 2; j++) {
            int sidx = wave + j * 4;               // 8 subtiles (128 rows)
            gld16(A + (m0 + sidx * 16 + st_row) * K + kt + st_gc,
                  lds + buf * 4096 + sidx * 512 + lane * 8);
        }
#pragma unroll
        for (int j = 0; j < 2; j++) {
            int sidx = wave + j * 4;
            gld16(Bm + (n0 + sidx * 16 + st_row) * K + kt + st_gc,
                  lds + 8192 + buf * 4096 + sidx * 512 + lane * 8);
        }
    };

    const int cfr = (lane >> 4) * 8;
    const int lr = lane & 15;
    auto LDFA = [&](int buf, int r) -> s16x8 {
        int off = buf * 4096 + ((r >> 4) << 9) + ((r & 15) << 5)
                + (cfr ^ (((r >> 3) & 1) << 4));
        return *(const s16x8*)(lds + off);
    };
    auto LDFB = [&](int buf, int r) -> s16x8 {
        int off = 8192 + buf * 4096 + ((r >> 4) << 9) + ((r & 15) << 5)
                + (cfr ^ (((r >> 3) & 1) << 4));
        return *(const s16x8*)(lds + off);
    };

    f32x4 zero = { 0.f, 0.f, 0.f, 0.f };
    f32x4 acc[4][4];
#pragma unroll
    for (int i = 0; i < 4; i++)
#pragma unroll
        for (int j = 0; j < 4; j++) acc[i][j] = zero;

    STAGE(0, 0);
    asm volatile("s_waitcnt vmcnt(0)" ::: "memory");
    BARRIER();

    for (int t = 0; t < NT; ++t) {
        const int cur = t & 1;
        if ((t + 1) < NT) STAGE((t + 1) & 1, (t + 1) * 32);

        s16x8 af[4], bf[4];
#pragma unroll
        for (int mi = 0; mi < 4; mi++) af[mi] = LDFA(cur, wm * 64 + mi * 16 + lr);
#pragma unroll
        for (int ni = 0; ni < 4; ni++) bf[ni] = LDFB(cur, wn * 64 + ni * 16 + lr);

        __builtin_amdgcn_s_setprio(1);
#pragma unroll
        for (int mi = 0; mi < 4; mi++)
#pragma unroll
            for (int ni = 0; ni < 4; ni++)
                acc[mi][ni] = __builtin_amdgcn_mfma_f32_16x16x32_bf16(af[mi], bf[ni], acc[mi][ni], 0, 0, 0);
        __builtin_amdgcn_s_setprio(0);

        asm volatile("s_waitcnt vmcnt(0)" ::: "memory");
        BARRIER();
    }

    const long crow = m0 + wm * 64 + ((lane >> 4) << 2);
    const long ccol = n0 + wn * 64 + (lane & 15);
#pragma unroll
    for (int mi = 0; mi < 4; mi++)
#pragma unroll
        for (int ni = 0; ni < 4; ni++)
#pragma unroll
            for (int r = 0; r < 4; r++)
                Cout[(crow + mi * 16 + r) * 2048 + ccol + ni * 16] = acc[mi][ni][r];
}

// ---------------- fused causal conv (K=4) + SiLU + transpose ----------------
__global__ __launch_bounds__(256) void convx_k(const ushort* __restrict__ xbc,
                                               const float* __restrict__ w,
                                               const float* __restrict__ bias,
                                               ushort* __restrict__ xbcc,
                                               ushort* __restrict__ xT,
                                               ushort* __restrict__ Bt) {
    __shared__ ushort xin[35][136];
    __shared__ ushort yL[32][132];
    const int stile = blockIdx.x, slot = blockIdx.y, bc = blockIdx.z;
    const int tid = threadIdx.x;
    const int cc = bc & 7;
    const long tbase = (long)bc * 256 + stile * 32;
    const int c0 = slot * 128;
    const bool head = (cc == 0 && stile == 0);

#pragma unroll
    for (int i = 0; i < 3; i++) {
        int u = tid + i * 256;
        if (u < 560) {
            int r = u >> 4, seg = u & 15;
            s16x8 v;
            if (head && r < 3) {
#pragma unroll
                for (int j = 0; j < 8; j++) v[j] = 0;
            } else {
                v = *(const s16x8*)&xbc[(tbase - 3 + r) * 4352 + c0 + seg * 8];
            }
            *(s16x8*)&xin[r][seg * 8] = v;
        }
    }
    __syncthreads();

    const int s_loc = tid >> 3, p0 = (tid & 7) * 16;
    ushort yo[16];
#pragma unroll
    for (int j = 0; j < 16; j++) {
        int c = p0 + j;
        float a = bias[c0 + c];
#pragma unroll
        for (int k = 0; k < 4; k++)
            a += bf2f(xin[s_loc + k][c]) * w[(c0 + c) * 4 + k];
        float yv = a / (1.f + __expf(-a));
        ushort ub = f2bf(yv);
        yo[j] = ub;
        yL[s_loc][c] = ub;
    }
    *(s16x8*)&xbcc[(tbase + s_loc) * 4352 + c0 + p0] = *(const s16x8*)&yo[0];
    *(s16x8*)&xbcc[(tbase + s_loc) * 4352 + c0 + p0 + 8] = *(const s16x8*)&yo[8];
    __syncthreads();

    if (slot < 33) {
        const int p = tid >> 1, s0 = (tid & 1) * 16;
        ushort o[16];
#pragma unroll
        for (int j = 0; j < 16; j++) o[j] = yL[s0 + j][p];
        ushort* dst = (slot < 32)
            ? (xT + ((long)(bc * 32 + slot) * 128 + p) * 256 + stile * 32 + s0)
            : (Bt + ((long)bc * 128 + p) * 256 + stile * 32 + s0);
        *(s16x8*)&dst[0] = *(const s16x8*)&o[0];
        *(s16x8*)&dst[8] = *(const s16x8*)&o[8];
    }
}

// ---------------- dt softplus/clip + per-chunk cumsum ----------------
__global__ void prep_k(const ushort* __restrict__ dtr, const float* __restrict__ dt_bias,
                       const float* __restrict__ A_log, float* __restrict__ dtp,
                       float* __restrict__ dacs) {
    const int bx = blockIdx.x;
    const int h = bx & 31, cc = (bx >> 5) & 7, bi = bx >> 8;
    const int lane = threadIdx.x;
    const float A = -__expf(A_log[h]);
    const float bsh = dt_bias[h];
    float v[4], cs[4];
    float run = 0.f;
#pragma unroll
    for (int j = 0; j < 4; j++) {
        int pos = cc * 256 + lane * 4 + j;
        float raw = bf2f(dtr[((long)(bi * 2048 + pos)) * 32 + h]) + bsh;
        float sp = (raw > 20.f) ? raw : log1pf(__expf(raw));
        float d = fminf(fmaxf(sp, 0.001f), 0.1f);
        v[j] = d;
        run += d * A;
        cs[j] = run;
    }
    float tot = run, pre = run;
    for (int off = 1; off < 64; off <<= 1) {
        float u = __shfl_up(pre, off, 64);
        if (lane >= off) pre += u;
    }
    float excl = pre - tot;
    const long base = ((long)(bi * 32 + h)) * 2048 + cc * 256 + lane * 4;
#pragma unroll
    for (int j = 0; j < 4; j++) { dtp[base + j] = v[j]; dacs[base + j] = excl + cs[j]; }
}

// ---------------- CB = C.B^T per chunk via MFMA ----------------
__global__ __launch_bounds__(256) void cb_mfma_k(const ushort* __restrict__ xbcc,
                                                 float* __restrict__ CB) {
    const int bid = blockIdx.x;
    const int sq = bid & 1, lq = (bid >> 1) & 1, bc = bid >> 2;
    const int tid = threadIdx.x, lane = tid & 63, wave = tid >> 6;
    const int wm = wave >> 1, wn = wave & 1;
    const long tbase = (long)bc * 256;

    f32x4 zero = { 0.f, 0.f, 0.f, 0.f };
    f32x4 acc[4][4];
#pragma unroll
    for (int i = 0; i < 4; i++)
#pragma unroll
        for (int j = 0; j < 4; j++) acc[i][j] = zero;

    for (int kst = 0; kst < 4; ++kst) {
        const int koff = kst * 32 + (lane >> 4) * 8;
        s16x8 a[4], b[4];
#pragma unroll
        for (int mi = 0; mi < 4; mi++) {
            int l = lq * 128 + wm * 64 + mi * 16 + (lane & 15);
            a[mi] = *(const s16x8*)&xbcc[(tbase + l) * 4352 + 4224 + koff];
        }
#pragma unroll
        for (int ni = 0; ni < 4; ni++) {
            int s = sq * 128 + wn * 64 + ni * 16 + (lane & 15);
            b[ni] = *(const s16x8*)&xbcc[(tbase + s) * 4352 + 4096 + koff];
        }
#pragma unroll
        for (int mi = 0; mi < 4; mi++)
#pragma unroll
            for (int ni = 0; ni < 4; ni++)
                acc[mi][ni] = __builtin_amdgcn_mfma_f32_16x16x32_bf16(a[mi], b[ni], acc[mi][ni], 0, 0, 0);
    }

    float* out = CB + (long)bc * 65536;
#pragma unroll
    for (int mi = 0; mi < 4; mi++)
#pragma unroll
        for (int ni = 0; ni < 4; ni++)
#pragma unroll
            for (int r = 0; r < 4; r++) {
                int l = lq * 128 + wm * 64 + mi * 16 + (lane >> 4) * 4 + r;
                int s = sq * 128 + wn * 64 + ni * 16 + (lane & 15);
                out[(long)l * 256 + s] = acc[mi][ni][r];
            }
}

// ---------------- fused intra+inter scan via MFMA (single yf write) --------
__global__ __launch_bounds__(256) void scan_mfma_k(const ushort* __restrict__ xT,
                                                   const float* __restrict__ CB,
                                                   const float* __restrict__ dtp,
                                                   const float* __restrict__ dacs,
                                                   const ushort* __restrict__ xbcc,
                                                   const float* __restrict__ st,
                                                   float* __restrict__ yf) {
    const int bx = blockIdx.x;
    const int ltile = bx & 1, h = (bx >> 1) & 31, cc = (bx >> 6) & 7, bi = bx >> 9;
    const int tid = threadIdx.x, lane = tid & 63, wave = tid >> 6;
    const int wm = wave >> 1, wn = wave & 1;

    __shared__ float dA_s[256];
    __shared__ float F_s[256];

    const long dbase = ((long)(bi * 32 + h)) * 2048 + cc * 256;
    {
        float a = dacs[dbase + tid];
        float r = dacs[dbase + (tid | 31)];
        dA_s[tid] = a;
        F_s[tid] = __expf(r - a) * dtp[dbase + tid];
    }
    __syncthreads();

    int lch[4];
    float dAl[4];
#pragma unroll
    for (int mi = 0; mi < 4; mi++) {
        lch[mi] = ltile * 128 + wm * 64 + mi * 16 + (lane & 15);
        dAl[mi] = dA_s[lch[mi]];
    }

    f32x4 zero = { 0.f, 0.f, 0.f, 0.f };
    f32x4 acc[4][4];
#pragma unroll
    for (int i = 0; i < 4; i++)
#pragma unroll
        for (int j = 0; j < 4; j++) acc[i][j] = zero;

    const long tbase = (long)bi * 2048 + cc * 256;
    const long cbbase = ((long)(bi * 8 + cc)) * 65536;
    const ushort* xrow = xT + (((long)(bi * 8 + cc) * 32 + h) * 128) * 256;
    const int nsb = ltile * 4 + 4;

    for (int sb = 0; sb < nsb; ++sb) {
        const int soff = sb * 32 + (lane >> 4) * 8;
        s16x8 bf[4];
#pragma unroll
        for (int ni = 0; ni < 4; ni++) {
            int p = wn * 64 + ni * 16 + (lane & 15);
            bf[ni] = *(const s16x8*)&xrow[(long)p * 256 + soff];
        }
        const float Rsb = dA_s[sb * 32 + 31];
        const int s0 = soff;
#pragma unroll
        for (int mi = 0; mi < 4; mi++) {
            const int lb = lch[mi] >> 5;
            if (sb > lb) continue;
            const float* cbrow = CB + cbbase + (long)lch[mi] * 256 + s0;
            float4 c0 = *(const float4*)cbrow;
            float4 c1 = *(const float4*)(cbrow + 4);
            float E = __expf(dAl[mi] - Rsb);
            float m[8];
            m[0] = c0.x * E * F_s[s0 + 0]; m[1] = c0.y * E * F_s[s0 + 1];
            m[2] = c0.z * E * F_s[s0 + 2]; m[3] = c0.w * E * F_s[s0 + 3];
            m[4] = c1.x * E * F_s[s0 + 4]; m[5] = c1.y * E * F_s[s0 + 5];
            m[6] = c1.z * E * F_s[s0 + 6]; m[7] = c1.w * E * F_s[s0 + 7];
            if (sb == lb) {
#pragma unroll
                for (int j = 0; j < 8; j++)
                    if (s0 + j > lch[mi]) m[j] = 0.f;
            }
            s16x8 a;
#pragma unroll
            for (int j = 0; j < 8; j++) a[j] = (short)f2bf(m[j]);
#pragma unroll
            for (int ni = 0; ni < 4; ni++)
                acc[mi][ni] = __builtin_amdgcn_mfma_f32_16x16x32_bf16(a, bf[ni], acc[mi][ni], 0, 0, 0);
        }
    }

    const float* sbase = st + (((long)(bi * 8 + cc) * 32 + h) * 128) * 128;
    float eAr[4];
#pragma unroll
    for (int mi = 0; mi < 4; mi++) eAr[mi] = __expf(dAl[mi]);
    for (int kk = 0; kk < 4; ++kk) {
        const int koff = kk * 32 + (lane >> 4) * 8;
        s16x8 a[4], b[4];
#pragma unroll
        for (int mi = 0; mi < 4; mi++) {
            s16x8 raw = *(const s16x8*)&xbcc[(tbase + lch[mi]) * 4352 + 4224 + koff];
#pragma unroll
            for (int j = 0; j < 8; j++)
                a[mi][j] = (short)f2bf(bf2f((ushort)raw[j]) * eAr[mi]);
        }
#pragma unroll
        for (int ni = 0; ni < 4; ni++) {
            int p = wn * 64 + ni * 16 + (lane & 15);
            const float* pr = sbase + (long)p * 128 + koff;
            float4 v0 = *(const float4*)pr;
            float4 v1 = *(const float4*)(pr + 4);
            b[ni][0] = (short)f2bf(v0.x); b[ni][1] = (short)f2bf(v0.y);
            b[ni][2] = (short)f2bf(v0.z); b[ni][3] = (short)f2bf(v0.w);
            b[ni][4] = (short)f2bf(v1.x); b[ni][5] = (short)f2bf(v1.y);
            b[ni][6] = (short)f2bf(v1.z); b[ni][7] = (short)f2bf(v1.w);
        }
#pragma unroll
        for (int mi = 0; mi < 4; mi++)
#pragma unroll
            for (int ni = 0; ni < 4; ni++)
                acc[mi][ni] = __builtin_amdgcn_mfma_f32_16x16x32_bf16(a[mi], b[ni], acc[mi][ni], 0, 0, 0);
    }

    const long crow = tbase + ltile * 128 + wm * 64 + ((lane >> 4) << 2);
    const int ccol = h * 128 + wn * 64 + (lane & 15);
#pragma unroll
    for (int mi = 0; mi < 4; mi++)
#pragma unroll
        for (int ni = 0; ni < 4; ni++)
#pragma unroll
            for (int r = 0; r < 4; r++)
                yf[(crow + mi * 16 + r) * 4096 + ccol + ni * 16] = acc[mi][ni][r];
}

// ---------------- per-chunk end states via MFMA ----------------
__global__ __launch_bounds__(256) void states_mfma_k(const ushort* __restrict__ xT,
                                                     const ushort* __restrict__ Bt,
                                                     const float* __restrict__ dtp,
                                                     const float* __restrict__ dacs,
                                                     float* __restrict__ states) {
    const int bx = blockIdx.x;
    const int h = bx & 31, cc = (bx >> 5) & 7, bi = bx >> 8;
    const int bc = bi * 8 + cc;
    const int tid = threadIdx.x, lane = tid & 63, wave = tid >> 6;
    const int wm = wave >> 1, wn = wave & 1;
    __shared__ float wl[256];
    const long dbase = ((long)(bi * 32 + h)) * 2048 + cc * 256;
    {
        float last = dacs[dbase + 255];
        wl[tid] = __expf(last - dacs[dbase + tid]) * dtp[dbase + tid];
    }
    __syncthreads();

    f32x4 zero = { 0.f, 0.f, 0.f, 0.f };
    f32x4 acc[4][4];
#pragma unroll
    for (int i = 0; i < 4; i++)
#pragma unroll
        for (int j = 0; j < 4; j++) acc[i][j] = zero;

    const ushort* xrow = xT + (((long)bc * 32 + h) * 128) * 256;
    const ushort* brow = Bt + ((long)bc * 128) * 256;

    for (int sb = 0; sb < 8; ++sb) {
        const int soff = sb * 32 + (lane >> 4) * 8;
        s16x8 a[4], b[4];
#pragma unroll
        for (int mi = 0; mi < 4; mi++) {
            int p = wm * 64 + mi * 16 + (lane & 15);
            s16x8 raw = *(const s16x8*)&xrow[(long)p * 256 + soff];
#pragma unroll
            for (int j = 0; j < 8; j++)
                a[mi][j] = (short)f2bf(bf2f((ushort)raw[j]) * wl[soff + j]);
        }
#pragma unroll
        for (int ni = 0; ni < 4; ni++) {
            int n = wn * 64 + ni * 16 + (lane & 15);
            b[ni] = *(const s16x8*)&brow[(long)n * 256 + soff];
        }
#pragma unroll
        for (int mi = 0; mi < 4; mi++)
#pragma unroll
            for (int ni = 0; ni < 4; ni++)
                acc[mi][ni] = __builtin_amdgcn_mfma_f32_16x16x32_bf16(a[mi], b[ni], acc[mi][ni], 0, 0, 0);
    }

    float* out = states + (((long)bc * 32 + h) * 128) * 128;
#pragma unroll
    for (int mi = 0; mi < 4; mi++)
#pragma unroll
        for (int ni = 0; ni < 4; ni++)
#pragma unroll
            for (int r = 0; r < 4; r++) {
                int p = wm * 64 + mi * 16 + (lane >> 4) * 4 + r;
                int n = wn * 64 + ni * 16 + (lane & 15);
                out[(long)p * 128 + n] = acc[mi][ni][r];
            }
}

// ---------------- chunk recurrence: states -> prev_states (in place) ----------------
__global__ void rec_k(float* __restrict__ states, const float* __restrict__ dacs) {
    const int i = blockIdx.x * 256 + threadIdx.x;
    const int n = i & 127, p = (i >> 7) & 127, h = (i >> 14) & 31, bi = i >> 19;
    const long dbase = ((long)(bi * 32 + h)) * 2048;
    float run = 0.f;
    for (int cc = 0; cc < 8; cc++) {
        const long off = ((((long)(bi * 8 + cc)) * 32 + h) * 128 + p) * 128 + n;
        float st = states[off];
        states[off] = run;
        float dec = dacs[dbase + cc * 256 + 255];
        run = run * __expf(dec) + st;
    }
}

// ---------------- gate (silu(z)) + D*x + RMSNorm -> bf16 ----------------
__global__ __launch_bounds__(256) void gate_rms_k(const float* __restrict__ y, const ushort* __restrict__ zbuf,
                                                  const ushort* __restrict__ xbcc, const float* __restrict__ Dv,
                                                  const float* __restrict__ norm_w, ushort* __restrict__ yb) {
    const int t = blockIdx.x, tid = threadIdx.x;
    const float* yr = &y[(long)t * 4096];
    const ushort* zr = &zbuf[(long)t * 4096];
    const ushort* xr = &xbcc[(long)t * 4352];
    float g[16];
    float ss = 0.f;
#pragma unroll
    for (int j = 0; j < 16; j++) {
        int i = j * 256 + tid;
        float z = bf2f(zr[i]);
        float yv = yr[i] + Dv[i >> 7] * bf2f(xr[i]);
        float gv = yv * (z / (1.f + __expf(-z)));
        g[j] = gv;
        ss += gv * gv;
    }
#pragma unroll
    for (int off = 32; off > 0; off >>= 1) ss += __shfl_xor(ss, off, 64);
    __shared__ float red[4];
    if ((tid & 63) == 0) red[tid >> 6] = ss;
    __syncthreads();
    float tot = red[0] + red[1] + red[2] + red[3];
    float sc = rsqrtf(tot * (1.f / 4096.f) + 1e-6f);
#pragma unroll
    for (int j = 0; j < 16; j++) {
        int i = j * 256 + tid;
        yb[(long)t * 4096 + i] = f2bf(g[j] * sc * norm_w[i]);
    }
}

// ---------------------------------------------------------------------------
extern "C" void kernel_launch(void* const* d_in, const int* in_sizes, int n_in,
                              void* d_out, int out_size, void* d_ws, size_t ws_size,
                              hipStream_t stream) {
    const float* x       = (const float*)d_in[0];
    const float* W_in    = (const float*)d_in[1];
    const float* conv_w  = (const float*)d_in[2];
    const float* conv_b  = (const float*)d_in[3];
    const float* dt_bias = (const float*)d_in[4];
    const float* A_log   = (const float*)d_in[5];
    const float* Dv      = (const float*)d_in[6];
    const float* norm_w  = (const float*)d_in[7];
    const float* W_out   = (const float*)d_in[8];

    char* w8 = (char*)d_ws;
    ushort* xb    = (ushort*)(w8 + 0L);
    ushort* xT    = (ushort*)(w8 + 0L);            // alias (xb dead after GEMM1)
    ushort* yb    = (ushort*)(w8 + 0L);            // alias (xT dead before gate)
    ushort* woutb = (ushort*)(w8 + 33554432L);
    ushort* Bt    = (ushort*)(w8 + 50331648L);
    ushort* zbuf  = (ushort*)(w8 + 52428800L);
    ushort* xbc   = (ushort*)(w8 + 85983232L);
    ushort* dtr   = (ushort*)(w8 + 121634816L);
    ushort* xbcc  = (ushort*)(w8 + 121896960L);
    float*  dtp   = (float*)(w8 + 157548544L);
    float*  dacs  = (float*)(w8 + 158072832L);
    float*  cb    = (float*)(w8 + 158597120L);
    float*  yf    = (float*)(w8 + 162791424L);
    ushort* winb  = (ushort*)(w8 + 162791424L);    // alias (dead before yf written)
    float*  st    = (float*)(w8 + 229900288L);

    cast_all_k<<<34048, 256, 0, stream>>>((const float4*)x, (const float4*)W_out,
                                          (const float4*)W_in, xb, woutb, winb);
    gemm1_k<<<736, 512, 0, stream>>>(xb, winb, zbuf, xbc, dtr);
    convx_k<<<dim3(8, 34, 16), 256, 0, stream>>>(xbc, conv_w, conv_b, xbcc, xT, Bt);
    prep_k<<<512, 64, 0, stream>>>(dtr, dt_bias, A_log, dtp, dacs);
    cb_mfma_k<<<64, 256, 0, stream>>>(xbcc, cb);
    states_mfma_k<<<512, 256, 0, stream>>>(xT, Bt, dtp, dacs, st);
    rec_k<<<4096, 256, 0, stream>>>(st, dacs);
    scan_mfma_k<<<1024, 256, 0, stream>>>(xT, cb, dtp, dacs, xbcc, st, yf);
    gate_rms_k<<<4096, 256, 0, stream>>>(yf, zbuf, xbcc, Dv, norm_w, yb);
    gemm2_k<<<512, 256, 0, stream>>>(yb, woutb, (float*)d_out);
}

// Round 13
// 459.336 us; speedup vs baseline: 2.3530x; 1.0316x over previous
//
#include <hip/hip_runtime.h>

// ---------------------------------------------------------------------------
// SSM (Mamba2-style) fused forward for MI355X.
// R13: consolidation. gemm1 = R9 verbatim (ring-3, 1 barrier/K-tile, counted
//      vmcnt(3) — best measured 172us; ring-2/2-block and frag-pipeline
//      variants falsified at 182-184us). gemm2 = R12 (128^2 ring-2).
//      yf -> bf16 (yh): scan writes bf16 once, gate reads bf16 (halves that
//      intermediate's traffic, ~12us).
// ws layout (bytes): unchanged; yh (33MB) lives at the old yf offset.
// ---------------------------------------------------------------------------

typedef short s16x8 __attribute__((ext_vector_type(8)));
typedef float f32x4 __attribute__((ext_vector_type(4)));

__device__ __forceinline__ float bf2f(ushort u) {
    return __builtin_bit_cast(float, (unsigned)u << 16);
}
__device__ __forceinline__ ushort f2bf(float f) {
    unsigned u = __builtin_bit_cast(unsigned, f);
    unsigned r = u + 0x7fffu + ((u >> 16) & 1u);
    return (ushort)(r >> 16);
}

__device__ __forceinline__ void gld16(const void* g, void* l) {
    __builtin_amdgcn_global_load_lds((__attribute__((address_space(1))) void*)g,
                                     (__attribute__((address_space(3))) void*)l, 16, 0, 0);
}

#define BARRIER() asm volatile("s_barrier" ::: "memory")

// ---------------- unified cast kernel ----------------
__global__ void cast_all_k(const float4* __restrict__ x, const float4* __restrict__ wout,
                           const float4* __restrict__ win, ushort* __restrict__ xb,
                           ushort* __restrict__ woutb, ushort* __restrict__ winb) {
    const long b = blockIdx.x, tid = threadIdx.x;
    if (b < 8192) {
        long i = b * 256 + tid;
        float4 v = x[i];
        ushort4 o = { f2bf(v.x), f2bf(v.y), f2bf(v.z), f2bf(v.w) };
        *(ushort4*)(xb + i * 4) = o;
    } else if (b < 16384) {
        long i = (b - 8192) * 256 + tid;
        float4 v = wout[i];
        ushort4 o = { f2bf(v.x), f2bf(v.y), f2bf(v.z), f2bf(v.w) };
        *(ushort4*)(woutb + i * 4) = o;
    } else {
        long i = (b - 16384) * 256 + tid;   // < 8832*2048/4
        ushort4 o;
        if (i < 4341760L) {                 // 8480*2048/4
            float4 v = win[i];
            o = { f2bf(v.x), f2bf(v.y), f2bf(v.z), f2bf(v.w) };
        } else {
            o = { 0, 0, 0, 0 };
        }
        *(ushort4*)(winb + i * 4) = o;
    }
}

// ---------------- GEMM1: 256x192 tile, BK=32, 3-ring, 1 barrier/K-tile ----
__global__ __launch_bounds__(512, 1) void gemm1_k(const ushort* __restrict__ A,
                                                  const ushort* __restrict__ Bm,
                                                  ushort* __restrict__ zbuf,
                                                  ushort* __restrict__ xbc,
                                                  ushort* __restrict__ dtr) {
    constexpr int K = 2048, NT = 64;
    __shared__ ushort lds[3 * 8192 + 3 * 6144];
    const int tid = threadIdx.x, lane = tid & 63, wave = tid >> 6;
    const int wm = wave >> 2, wn = wave & 3;
    const int bid = blockIdx.x;
    const int xcd = bid & 7, w = bid >> 3;      // w in [0,92)
    const int mt = xcd * 2 + (w & 1), nt = w >> 1;
    const long m0 = (long)mt * 256, n0 = (long)nt * 192;

    const int st_row = lane >> 2;
    const int st_gc = ((lane & 3) * 8) ^ (((lane >> 5) & 1) << 4);

    auto STAGE_A = [&](int buf, int kt) {
#pragma unroll
        for (int j = 0; j < 2; j++) {
            int sidx = wave + j * 8;
            gld16(A + (m0 + sidx * 16 + st_row) * K + kt + st_gc,
                  lds + buf * 8192 + sidx * 512 + lane * 8);
        }
    };
    auto STAGE_B = [&](int buf, int kt) {
#pragma unroll
        for (int j = 0; j < 2; j++) {
            int sidx = wave + j * 8;
            if (sidx < 12)
                gld16(Bm + (n0 + sidx * 16 + st_row) * K + kt + st_gc,
                      lds + 24576 + buf * 6144 + sidx * 512 + lane * 8);
        }
    };

    const int cfr = (lane >> 4) * 8;
    const int lr = lane & 15;
    auto LDFA = [&](int buf, int r) -> s16x8 {
        int off = buf * 8192 + ((r >> 4) << 9) + ((r & 15) << 5)
                + (cfr ^ (((r >> 3) & 1) << 4));
        return *(const s16x8*)(lds + off);
    };
    auto LDFB = [&](int buf, int r) -> s16x8 {
        int off = 24576 + buf * 6144 + ((r >> 4) << 9) + ((r & 15) << 5)
                + (cfr ^ (((r >> 3) & 1) << 4));
        return *(const s16x8*)(lds + off);
    };

    f32x4 zero = { 0.f, 0.f, 0.f, 0.f };
    f32x4 acc[8][3];
#pragma unroll
    for (int i = 0; i < 8; i++)
#pragma unroll
        for (int j = 0; j < 3; j++) acc[i][j] = zero;

    STAGE_A(0, 0);  STAGE_B(0, 0);
    STAGE_A(1, 32); STAGE_B(1, 32);
    asm volatile("s_waitcnt vmcnt(3)" ::: "memory");
    BARRIER();

    for (int t = 0; t < NT; ++t) {
        const int cur = t % 3;
        const int nxt = (t + 2) % 3;
        const int kt2 = (t + 2) * 32;
        const bool do_stage = (t + 2) < NT;

        s16x8 bfr[3], alo[4], ahi[4];
#pragma unroll
        for (int ni = 0; ni < 3; ni++) bfr[ni] = LDFB(cur, wn * 48 + ni * 16 + lr);
#pragma unroll
        for (int mi = 0; mi < 4; mi++) alo[mi] = LDFA(cur, wm * 128 + mi * 16 + lr);
#pragma unroll
        for (int mi = 0; mi < 4; mi++) ahi[mi] = LDFA(cur, wm * 128 + 64 + mi * 16 + lr);
        if (do_stage) { STAGE_A(nxt, kt2); STAGE_B(nxt, kt2); }

        __builtin_amdgcn_s_setprio(1);
#pragma unroll
        for (int mi = 0; mi < 4; mi++)
#pragma unroll
            for (int ni = 0; ni < 3; ni++)
                acc[mi][ni] = __builtin_amdgcn_mfma_f32_16x16x32_bf16(alo[mi], bfr[ni], acc[mi][ni], 0, 0, 0);
#pragma unroll
        for (int mi = 0; mi < 4; mi++)
#pragma unroll
            for (int ni = 0; ni < 3; ni++)
                acc[mi + 4][ni] = __builtin_amdgcn_mfma_f32_16x16x32_bf16(ahi[mi], bfr[ni], acc[mi + 4][ni], 0, 0, 0);
        __builtin_amdgcn_s_setprio(0);

        if (do_stage) asm volatile("s_waitcnt vmcnt(3)" ::: "memory");
        else          asm volatile("s_waitcnt vmcnt(0)" ::: "memory");
        BARRIER();
    }

    const int lr4 = (lane >> 4) * 4;
#pragma unroll
    for (int mi = 0; mi < 8; mi++) {
#pragma unroll
        for (int ni = 0; ni < 3; ni++) {
            const long col = n0 + wn * 48 + ni * 16 + lr;
            ushort* dst;
            long stride;
            if (col < 4096)      { dst = zbuf + col;         stride = 4096; }
            else if (col < 8448) { dst = xbc + (col - 4096); stride = 4352; }
            else if (col < 8480) { dst = dtr + (col - 8448); stride = 32;   }
            else continue;
            const long row0 = m0 + wm * 128 + mi * 16 + lr4;
#pragma unroll
            for (int r = 0; r < 4; r++) dst[(row0 + r) * stride] = f2bf(acc[mi][ni][r]);
        }
    }
}

// ---------------- GEMM2: 128x128 tile, BK=32, ring-2, grid 512 ------------
__global__ __launch_bounds__(256) void gemm2_k(const ushort* __restrict__ A,
                                               const ushort* __restrict__ Bm,
                                               float* __restrict__ Cout) {
    constexpr int K = 4096, NT = 128;
    __shared__ ushort lds[2 * 4096 + 2 * 4096];   // 32 KB
    const int tid = threadIdx.x, lane = tid & 63, wave = tid >> 6;
    const int wm = wave >> 1, wn = wave & 1;
    const int bid = blockIdx.x;                    // 512 = 8 x (4 mt x 16 nt)
    const int xcd = bid & 7, w = bid >> 3;
    const int mt = xcd * 4 + (w & 3), nt = w >> 2;
    const long m0 = (long)mt * 128, n0 = (long)nt * 128;

    const int st_row = lane >> 2;
    const int st_gc = ((lane & 3) * 8) ^ (((lane >> 5) & 1) << 4);

    auto STAGE = [&](int buf, int kt) {
#pragma unroll
        for (int j = 0; j < 2; j++) {
            int sidx = wave + j * 4;               // 8 subtiles (128 rows)
            gld16(A + (m0 + sidx * 16 + st_row) * K + kt + st_gc,
                  lds + buf * 4096 + sidx * 512 + lane * 8);
        }
#pragma unroll
        for (int j = 0; j < 2; j++) {
            int sidx = wave + j * 4;
            gld16(Bm + (n0 + sidx * 16 + st_row) * K + kt + st_gc,
                  lds + 8192 + buf * 4096 + sidx * 512 + lane * 8);
        }
    };

    const int cfr = (lane >> 4) * 8;
    const int lr = lane & 15;
    auto LDFA = [&](int buf, int r) -> s16x8 {
        int off = buf * 4096 + ((r >> 4) << 9) + ((r & 15) << 5)
                + (cfr ^ (((r >> 3) & 1) << 4));
        return *(const s16x8*)(lds + off);
    };
    auto LDFB = [&](int buf, int r) -> s16x8 {
        int off = 8192 + buf * 4096 + ((r >> 4) << 9) + ((r & 15) << 5)
                + (cfr ^ (((r >> 3) & 1) << 4));
        return *(const s16x8*)(lds + off);
    };

    f32x4 zero = { 0.f, 0.f, 0.f, 0.f };
    f32x4 acc[4][4];
#pragma unroll
    for (int i = 0; i < 4; i++)
#pragma unroll
        for (int j = 0; j < 4; j++) acc[i][j] = zero;

    STAGE(0, 0);
    asm volatile("s_waitcnt vmcnt(0)" ::: "memory");
    BARRIER();

    for (int t = 0; t < NT; ++t) {
        const int cur = t & 1;
        if ((t + 1) < NT) STAGE((t + 1) & 1, (t + 1) * 32);

        s16x8 af[4], bf[4];
#pragma unroll
        for (int mi = 0; mi < 4; mi++) af[mi] = LDFA(cur, wm * 64 + mi * 16 + lr);
#pragma unroll
        for (int ni = 0; ni < 4; ni++) bf[ni] = LDFB(cur, wn * 64 + ni * 16 + lr);

        __builtin_amdgcn_s_setprio(1);
#pragma unroll
        for (int mi = 0; mi < 4; mi++)
#pragma unroll
            for (int ni = 0; ni < 4; ni++)
                acc[mi][ni] = __builtin_amdgcn_mfma_f32_16x16x32_bf16(af[mi], bf[ni], acc[mi][ni], 0, 0, 0);
        __builtin_amdgcn_s_setprio(0);

        asm volatile("s_waitcnt vmcnt(0)" ::: "memory");
        BARRIER();
    }

    const long crow = m0 + wm * 64 + ((lane >> 4) << 2);
    const long ccol = n0 + wn * 64 + (lane & 15);
#pragma unroll
    for (int mi = 0; mi < 4; mi++)
#pragma unroll
        for (int ni = 0; ni < 4; ni++)
#pragma unroll
            for (int r = 0; r < 4; r++)
                Cout[(crow + mi * 16 + r) * 2048 + ccol + ni * 16] = acc[mi][ni][r];
}

// ---------------- fused causal conv (K=4) + SiLU + transpose ----------------
__global__ __launch_bounds__(256) void convx_k(const ushort* __restrict__ xbc,
                                               const float* __restrict__ w,
                                               const float* __restrict__ bias,
                                               ushort* __restrict__ xbcc,
                                               ushort* __restrict__ xT,
                                               ushort* __restrict__ Bt) {
    __shared__ ushort xin[35][136];
    __shared__ ushort yL[32][132];
    const int stile = blockIdx.x, slot = blockIdx.y, bc = blockIdx.z;
    const int tid = threadIdx.x;
    const int cc = bc & 7;
    const long tbase = (long)bc * 256 + stile * 32;
    const int c0 = slot * 128;
    const bool head = (cc == 0 && stile == 0);

#pragma unroll
    for (int i = 0; i < 3; i++) {
        int u = tid + i * 256;
        if (u < 560) {
            int r = u >> 4, seg = u & 15;
            s16x8 v;
            if (head && r < 3) {
#pragma unroll
                for (int j = 0; j < 8; j++) v[j] = 0;
            } else {
                v = *(const s16x8*)&xbc[(tbase - 3 + r) * 4352 + c0 + seg * 8];
            }
            *(s16x8*)&xin[r][seg * 8] = v;
        }
    }
    __syncthreads();

    const int s_loc = tid >> 3, p0 = (tid & 7) * 16;
    ushort yo[16];
#pragma unroll
    for (int j = 0; j < 16; j++) {
        int c = p0 + j;
        float a = bias[c0 + c];
#pragma unroll
        for (int k = 0; k < 4; k++)
            a += bf2f(xin[s_loc + k][c]) * w[(c0 + c) * 4 + k];
        float yv = a / (1.f + __expf(-a));
        ushort ub = f2bf(yv);
        yo[j] = ub;
        yL[s_loc][c] = ub;
    }
    *(s16x8*)&xbcc[(tbase + s_loc) * 4352 + c0 + p0] = *(const s16x8*)&yo[0];
    *(s16x8*)&xbcc[(tbase + s_loc) * 4352 + c0 + p0 + 8] = *(const s16x8*)&yo[8];
    __syncthreads();

    if (slot < 33) {
        const int p = tid >> 1, s0 = (tid & 1) * 16;
        ushort o[16];
#pragma unroll
        for (int j = 0; j < 16; j++) o[j] = yL[s0 + j][p];
        ushort* dst = (slot < 32)
            ? (xT + ((long)(bc * 32 + slot) * 128 + p) * 256 + stile * 32 + s0)
            : (Bt + ((long)bc * 128 + p) * 256 + stile * 32 + s0);
        *(s16x8*)&dst[0] = *(const s16x8*)&o[0];
        *(s16x8*)&dst[8] = *(const s16x8*)&o[8];
    }
}

// ---------------- dt softplus/clip + per-chunk cumsum ----------------
__global__ void prep_k(const ushort* __restrict__ dtr, const float* __restrict__ dt_bias,
                       const float* __restrict__ A_log, float* __restrict__ dtp,
                       float* __restrict__ dacs) {
    const int bx = blockIdx.x;
    const int h = bx & 31, cc = (bx >> 5) & 7, bi = bx >> 8;
    const int lane = threadIdx.x;
    const float A = -__expf(A_log[h]);
    const float bsh = dt_bias[h];
    float v[4], cs[4];
    float run = 0.f;
#pragma unroll
    for (int j = 0; j < 4; j++) {
        int pos = cc * 256 + lane * 4 + j;
        float raw = bf2f(dtr[((long)(bi * 2048 + pos)) * 32 + h]) + bsh;
        float sp = (raw > 20.f) ? raw : log1pf(__expf(raw));
        float d = fminf(fmaxf(sp, 0.001f), 0.1f);
        v[j] = d;
        run += d * A;
        cs[j] = run;
    }
    float tot = run, pre = run;
    for (int off = 1; off < 64; off <<= 1) {
        float u = __shfl_up(pre, off, 64);
        if (lane >= off) pre += u;
    }
    float excl = pre - tot;
    const long base = ((long)(bi * 32 + h)) * 2048 + cc * 256 + lane * 4;
#pragma unroll
    for (int j = 0; j < 4; j++) { dtp[base + j] = v[j]; dacs[base + j] = excl + cs[j]; }
}

// ---------------- CB = C.B^T per chunk via MFMA ----------------
__global__ __launch_bounds__(256) void cb_mfma_k(const ushort* __restrict__ xbcc,
                                                 float* __restrict__ CB) {
    const int bid = blockIdx.x;
    const int sq = bid & 1, lq = (bid >> 1) & 1, bc = bid >> 2;
    const int tid = threadIdx.x, lane = tid & 63, wave = tid >> 6;
    const int wm = wave >> 1, wn = wave & 1;
    const long tbase = (long)bc * 256;

    f32x4 zero = { 0.f, 0.f, 0.f, 0.f };
    f32x4 acc[4][4];
#pragma unroll
    for (int i = 0; i < 4; i++)
#pragma unroll
        for (int j = 0; j < 4; j++) acc[i][j] = zero;

    for (int kst = 0; kst < 4; ++kst) {
        const int koff = kst * 32 + (lane >> 4) * 8;
        s16x8 a[4], b[4];
#pragma unroll
        for (int mi = 0; mi < 4; mi++) {
            int l = lq * 128 + wm * 64 + mi * 16 + (lane & 15);
            a[mi] = *(const s16x8*)&xbcc[(tbase + l) * 4352 + 4224 + koff];
        }
#pragma unroll
        for (int ni = 0; ni < 4; ni++) {
            int s = sq * 128 + wn * 64 + ni * 16 + (lane & 15);
            b[ni] = *(const s16x8*)&xbcc[(tbase + s) * 4352 + 4096 + koff];
        }
#pragma unroll
        for (int mi = 0; mi < 4; mi++)
#pragma unroll
            for (int ni = 0; ni < 4; ni++)
                acc[mi][ni] = __builtin_amdgcn_mfma_f32_16x16x32_bf16(a[mi], b[ni], acc[mi][ni], 0, 0, 0);
    }

    float* out = CB + (long)bc * 65536;
#pragma unroll
    for (int mi = 0; mi < 4; mi++)
#pragma unroll
        for (int ni = 0; ni < 4; ni++)
#pragma unroll
            for (int r = 0; r < 4; r++) {
                int l = lq * 128 + wm * 64 + mi * 16 + (lane >> 4) * 4 + r;
                int s = sq * 128 + wn * 64 + ni * 16 + (lane & 15);
                out[(long)l * 256 + s] = acc[mi][ni][r];
            }
}

// ---------------- fused intra+inter scan via MFMA (single bf16 write) ------
__global__ __launch_bounds__(256) void scan_mfma_k(const ushort* __restrict__ xT,
                                                   const float* __restrict__ CB,
                                                   const float* __restrict__ dtp,
                                                   const float* __restrict__ dacs,
                                                   const ushort* __restrict__ xbcc,
                                                   const float* __restrict__ st,
                                                   ushort* __restrict__ yh) {
    const int bx = blockIdx.x;
    const int ltile = bx & 1, h = (bx >> 1) & 31, cc = (bx >> 6) & 7, bi = bx >> 9;
    const int tid = threadIdx.x, lane = tid & 63, wave = tid >> 6;
    const int wm = wave >> 1, wn = wave & 1;

    __shared__ float dA_s[256];
    __shared__ float F_s[256];

    const long dbase = ((long)(bi * 32 + h)) * 2048 + cc * 256;
    {
        float a = dacs[dbase + tid];
        float r = dacs[dbase + (tid | 31)];
        dA_s[tid] = a;
        F_s[tid] = __expf(r - a) * dtp[dbase + tid];
    }
    __syncthreads();

    int lch[4];
    float dAl[4];
#pragma unroll
    for (int mi = 0; mi < 4; mi++) {
        lch[mi] = ltile * 128 + wm * 64 + mi * 16 + (lane & 15);
        dAl[mi] = dA_s[lch[mi]];
    }

    f32x4 zero = { 0.f, 0.f, 0.f, 0.f };
    f32x4 acc[4][4];
#pragma unroll
    for (int i = 0; i < 4; i++)
#pragma unroll
        for (int j = 0; j < 4; j++) acc[i][j] = zero;

    const long tbase = (long)bi * 2048 + cc * 256;
    const long cbbase = ((long)(bi * 8 + cc)) * 65536;
    const ushort* xrow = xT + (((long)(bi * 8 + cc) * 32 + h) * 128) * 256;
    const int nsb = ltile * 4 + 4;

    for (int sb = 0; sb < nsb; ++sb) {
        const int soff = sb * 32 + (lane >> 4) * 8;
        s16x8 bf[4];
#pragma unroll
        for (int ni = 0; ni < 4; ni++) {
            int p = wn * 64 + ni * 16 + (lane & 15);
            bf[ni] = *(const s16x8*)&xrow[(long)p * 256 + soff];
        }
        const float Rsb = dA_s[sb * 32 + 31];
        const int s0 = soff;
#pragma unroll
        for (int mi = 0; mi < 4; mi++) {
            const int lb = lch[mi] >> 5;
            if (sb > lb) continue;
            const float* cbrow = CB + cbbase + (long)lch[mi] * 256 + s0;
            float4 c0 = *(const float4*)cbrow;
            float4 c1 = *(const float4*)(cbrow + 4);
            float E = __expf(dAl[mi] - Rsb);
            float m[8];
            m[0] = c0.x * E * F_s[s0 + 0]; m[1] = c0.y * E * F_s[s0 + 1];
            m[2] = c0.z * E * F_s[s0 + 2]; m[3] = c0.w * E * F_s[s0 + 3];
            m[4] = c1.x * E * F_s[s0 + 4]; m[5] = c1.y * E * F_s[s0 + 5];
            m[6] = c1.z * E * F_s[s0 + 6]; m[7] = c1.w * E * F_s[s0 + 7];
            if (sb == lb) {
#pragma unroll
                for (int j = 0; j < 8; j++)
                    if (s0 + j > lch[mi]) m[j] = 0.f;
            }
            s16x8 a;
#pragma unroll
            for (int j = 0; j < 8; j++) a[j] = (short)f2bf(m[j]);
#pragma unroll
            for (int ni = 0; ni < 4; ni++)
                acc[mi][ni] = __builtin_amdgcn_mfma_f32_16x16x32_bf16(a, bf[ni], acc[mi][ni], 0, 0, 0);
        }
    }

    const float* sbase = st + (((long)(bi * 8 + cc) * 32 + h) * 128) * 128;
    float eAr[4];
#pragma unroll
    for (int mi = 0; mi < 4; mi++) eAr[mi] = __expf(dAl[mi]);
    for (int kk = 0; kk < 4; ++kk) {
        const int koff = kk * 32 + (lane >> 4) * 8;
        s16x8 a[4], b[4];
#pragma unroll
        for (int mi = 0; mi < 4; mi++) {
            s16x8 raw = *(const s16x8*)&xbcc[(tbase + lch[mi]) * 4352 + 4224 + koff];
#pragma unroll
            for (int j = 0; j < 8; j++)
                a[mi][j] = (short)f2bf(bf2f((ushort)raw[j]) * eAr[mi]);
        }
#pragma unroll
        for (int ni = 0; ni < 4; ni++) {
            int p = wn * 64 + ni * 16 + (lane & 15);
            const float* pr = sbase + (long)p * 128 + koff;
            float4 v0 = *(const float4*)pr;
            float4 v1 = *(const float4*)(pr + 4);
            b[ni][0] = (short)f2bf(v0.x); b[ni][1] = (short)f2bf(v0.y);
            b[ni][2] = (short)f2bf(v0.z); b[ni][3] = (short)f2bf(v0.w);
            b[ni][4] = (short)f2bf(v1.x); b[ni][5] = (short)f2bf(v1.y);
            b[ni][6] = (short)f2bf(v1.z); b[ni][7] = (short)f2bf(v1.w);
        }
#pragma unroll
        for (int mi = 0; mi < 4; mi++)
#pragma unroll
            for (int ni = 0; ni < 4; ni++)
                acc[mi][ni] = __builtin_amdgcn_mfma_f32_16x16x32_bf16(a[mi], b[ni], acc[mi][ni], 0, 0, 0);
    }

    const long crow = tbase + ltile * 128 + wm * 64 + ((lane >> 4) << 2);
    const int ccol = h * 128 + wn * 64 + (lane & 15);
#pragma unroll
    for (int mi = 0; mi < 4; mi++)
#pragma unroll
        for (int ni = 0; ni < 4; ni++)
#pragma unroll
            for (int r = 0; r < 4; r++)
                yh[(crow + mi * 16 + r) * 4096 + ccol + ni * 16] = f2bf(acc[mi][ni][r]);
}

// ---------------- per-chunk end states via MFMA ----------------
__global__ __launch_bounds__(256) void states_mfma_k(const ushort* __restrict__ xT,
                                                     const ushort* __restrict__ Bt,
                                                     const float* __restrict__ dtp,
                                                     const float* __restrict__ dacs,
                                                     float* __restrict__ states) {
    const int bx = blockIdx.x;
    const int h = bx & 31, cc = (bx >> 5) & 7, bi = bx >> 8;
    const int bc = bi * 8 + cc;
    const int tid = threadIdx.x, lane = tid & 63, wave = tid >> 6;
    const int wm = wave >> 1, wn = wave & 1;
    __shared__ float wl[256];
    const long dbase = ((long)(bi * 32 + h)) * 2048 + cc * 256;
    {
        float last = dacs[dbase + 255];
        wl[tid] = __expf(last - dacs[dbase + tid]) * dtp[dbase + tid];
    }
    __syncthreads();

    f32x4 zero = { 0.f, 0.f, 0.f, 0.f };
    f32x4 acc[4][4];
#pragma unroll
    for (int i = 0; i < 4; i++)
#pragma unroll
        for (int j = 0; j < 4; j++) acc[i][j] = zero;

    const ushort* xrow = xT + (((long)bc * 32 + h) * 128) * 256;
    const ushort* brow = Bt + ((long)bc * 128) * 256;

    for (int sb = 0; sb < 8; ++sb) {
        const int soff = sb * 32 + (lane >> 4) * 8;
        s16x8 a[4], b[4];
#pragma unroll
        for (int mi = 0; mi < 4; mi++) {
            int p = wm * 64 + mi * 16 + (lane & 15);
            s16x8 raw = *(const s16x8*)&xrow[(long)p * 256 + soff];
#pragma unroll
            for (int j = 0; j < 8; j++)
                a[mi][j] = (short)f2bf(bf2f((ushort)raw[j]) * wl[soff + j]);
        }
#pragma unroll
        for (int ni = 0; ni < 4; ni++) {
            int n = wn * 64 + ni * 16 + (lane & 15);
            b[ni] = *(const s16x8*)&brow[(long)n * 256 + soff];
        }
#pragma unroll
        for (int mi = 0; mi < 4; mi++)
#pragma unroll
            for (int ni = 0; ni < 4; ni++)
                acc[mi][ni] = __builtin_amdgcn_mfma_f32_16x16x32_bf16(a[mi], b[ni], acc[mi][ni], 0, 0, 0);
    }

    float* out = states + (((long)bc * 32 + h) * 128) * 128;
#pragma unroll
    for (int mi = 0; mi < 4; mi++)
#pragma unroll
        for (int ni = 0; ni < 4; ni++)
#pragma unroll
            for (int r = 0; r < 4; r++) {
                int p = wm * 64 + mi * 16 + (lane >> 4) * 4 + r;
                int n = wn * 64 + ni * 16 + (lane & 15);
                out[(long)p * 128 + n] = acc[mi][ni][r];
            }
}

// ---------------- chunk recurrence: states -> prev_states (in place) ----------------
__global__ void rec_k(float* __restrict__ states, const float* __restrict__ dacs) {
    const int i = blockIdx.x * 256 + threadIdx.x;
    const int n = i & 127, p = (i >> 7) & 127, h = (i >> 14) & 31, bi = i >> 19;
    const long dbase = ((long)(bi * 32 + h)) * 2048;
    float run = 0.f;
    for (int cc = 0; cc < 8; cc++) {
        const long off = ((((long)(bi * 8 + cc)) * 32 + h) * 128 + p) * 128 + n;
        float st = states[off];
        states[off] = run;
        float dec = dacs[dbase + cc * 256 + 255];
        run = run * __expf(dec) + st;
    }
}

// ---------------- gate (silu(z)) + D*x + RMSNorm -> bf16 ----------------
__global__ __launch_bounds__(256) void gate_rms_k(const ushort* __restrict__ yh, const ushort* __restrict__ zbuf,
                                                  const ushort* __restrict__ xbcc, const float* __restrict__ Dv,
                                                  const float* __restrict__ norm_w, ushort* __restrict__ yb) {
    const int t = blockIdx.x, tid = threadIdx.x;
    const ushort* yr = &yh[(long)t * 4096];
    const ushort* zr = &zbuf[(long)t * 4096];
    const ushort* xr = &xbcc[(long)t * 4352];
    float g[16];
    float ss = 0.f;
#pragma unroll
    for (int j = 0; j < 16; j++) {
        int i = j * 256 + tid;
        float z = bf2f(zr[i]);
        float yv = bf2f(yr[i]) + Dv[i >> 7] * bf2f(xr[i]);
        float gv = yv * (z / (1.f + __expf(-z)));
        g[j] = gv;
        ss += gv * gv;
    }
#pragma unroll
    for (int off = 32; off > 0; off >>= 1) ss += __shfl_xor(ss, off, 64);
    __shared__ float red[4];
    if ((tid & 63) == 0) red[tid >> 6] = ss;
    __syncthreads();
    float tot = red[0] + red[1] + red[2] + red[3];
    float sc = rsqrtf(tot * (1.f / 4096.f) + 1e-6f);
#pragma unroll
    for (int j = 0; j < 16; j++) {
        int i = j * 256 + tid;
        yb[(long)t * 4096 + i] = f2bf(g[j] * sc * norm_w[i]);
    }
}

// ---------------------------------------------------------------------------
extern "C" void kernel_launch(void* const* d_in, const int* in_sizes, int n_in,
                              void* d_out, int out_size, void* d_ws, size_t ws_size,
                              hipStream_t stream) {
    const float* x       = (const float*)d_in[0];
    const float* W_in    = (const float*)d_in[1];
    const float* conv_w  = (const float*)d_in[2];
    const float* conv_b  = (const float*)d_in[3];
    const float* dt_bias = (const float*)d_in[4];
    const float* A_log   = (const float*)d_in[5];
    const float* Dv      = (const float*)d_in[6];
    const float* norm_w  = (const float*)d_in[7];
    const float* W_out   = (const float*)d_in[8];

    char* w8 = (char*)d_ws;
    ushort* xb    = (ushort*)(w8 + 0L);
    ushort* xT    = (ushort*)(w8 + 0L);            // alias (xb dead after GEMM1)
    ushort* yb    = (ushort*)(w8 + 0L);            // alias (xT dead before gate)
    ushort* woutb = (ushort*)(w8 + 33554432L);
    ushort* Bt    = (ushort*)(w8 + 50331648L);
    ushort* zbuf  = (ushort*)(w8 + 52428800L);
    ushort* xbc   = (ushort*)(w8 + 85983232L);
    ushort* dtr   = (ushort*)(w8 + 121634816L);
    ushort* xbcc  = (ushort*)(w8 + 121896960L);
    float*  dtp   = (float*)(w8 + 157548544L);
    float*  dacs  = (float*)(w8 + 158072832L);
    float*  cb    = (float*)(w8 + 158597120L);
    ushort* yh    = (ushort*)(w8 + 162791424L);    // bf16 scan output
    ushort* winb  = (ushort*)(w8 + 162791424L);    // alias (dead before yh written)
    float*  st    = (float*)(w8 + 229900288L);

    cast_all_k<<<34048, 256, 0, stream>>>((const float4*)x, (const float4*)W_out,
                                          (const float4*)W_in, xb, woutb, winb);
    gemm1_k<<<736, 512, 0, stream>>>(xb, winb, zbuf, xbc, dtr);
    convx_k<<<dim3(8, 34, 16), 256, 0, stream>>>(xbc, conv_w, conv_b, xbcc, xT, Bt);
    prep_k<<<512, 64, 0, stream>>>(dtr, dt_bias, A_log, dtp, dacs);
    cb_mfma_k<<<64, 256, 0, stream>>>(xbcc, cb);
    states_mfma_k<<<512, 256, 0, stream>>>(xT, Bt, dtp, dacs, st);
    rec_k<<<4096, 256, 0, stream>>>(st, dacs);
    scan_mfma_k<<<1024, 256, 0, stream>>>(xT, cb, dtp, dacs, xbcc, st, yh);
    gate_rms_k<<<4096, 256, 0, stream>>>(yh, zbuf, xbcc, Dv, norm_w, yb);
    gemm2_k<<<512, 256, 0, stream>>>(yb, woutb, (float*)d_out);
}

// Round 14
// 459.182 us; speedup vs baseline: 2.3537x; 1.0003x over previous
//
#include <hip/hip_runtime.h>

// ---------------------------------------------------------------------------
// SSM (Mamba2-style) fused forward for MI355X.
// R14: gemm1 -> m201-style fine-phase schedule: BK=64, dbuf-2 (112KB LDS),
//      4 phases per K-tile, each {ds_read quadrant (+B in ph0) | stage |
//      barrier | setprio MFMA x12 | barrier}; staging confined to ph0/ph1 so
//      the tile-end vmcnt(0) drains ~1000-cycle-old loads. Everything else
//      identical to R13 (best: 459us, absmax 0.03125).
// ws layout (bytes): unchanged.
// ---------------------------------------------------------------------------

typedef short s16x8 __attribute__((ext_vector_type(8)));
typedef float f32x4 __attribute__((ext_vector_type(4)));

__device__ __forceinline__ float bf2f(ushort u) {
    return __builtin_bit_cast(float, (unsigned)u << 16);
}
__device__ __forceinline__ ushort f2bf(float f) {
    unsigned u = __builtin_bit_cast(unsigned, f);
    unsigned r = u + 0x7fffu + ((u >> 16) & 1u);
    return (ushort)(r >> 16);
}

__device__ __forceinline__ void gld16(const void* g, void* l) {
    __builtin_amdgcn_global_load_lds((__attribute__((address_space(1))) void*)g,
                                     (__attribute__((address_space(3))) void*)l, 16, 0, 0);
}

#define BARRIER() asm volatile("s_barrier" ::: "memory")

// ---------------- unified cast kernel ----------------
__global__ void cast_all_k(const float4* __restrict__ x, const float4* __restrict__ wout,
                           const float4* __restrict__ win, ushort* __restrict__ xb,
                           ushort* __restrict__ woutb, ushort* __restrict__ winb) {
    const long b = blockIdx.x, tid = threadIdx.x;
    if (b < 8192) {
        long i = b * 256 + tid;
        float4 v = x[i];
        ushort4 o = { f2bf(v.x), f2bf(v.y), f2bf(v.z), f2bf(v.w) };
        *(ushort4*)(xb + i * 4) = o;
    } else if (b < 16384) {
        long i = (b - 8192) * 256 + tid;
        float4 v = wout[i];
        ushort4 o = { f2bf(v.x), f2bf(v.y), f2bf(v.z), f2bf(v.w) };
        *(ushort4*)(woutb + i * 4) = o;
    } else {
        long i = (b - 16384) * 256 + tid;   // < 8832*2048/4
        ushort4 o;
        if (i < 4341760L) {                 // 8480*2048/4
            float4 v = win[i];
            o = { f2bf(v.x), f2bf(v.y), f2bf(v.z), f2bf(v.w) };
        } else {
            o = { 0, 0, 0, 0 };
        }
        *(ushort4*)(winb + i * 4) = o;
    }
}

// ---------------- GEMM1: 256x192 tile, BK=64, dbuf-2, 4 fine phases -------
__global__ __launch_bounds__(512, 1) void gemm1_k(const ushort* __restrict__ A,
                                                  const ushort* __restrict__ Bm,
                                                  ushort* __restrict__ zbuf,
                                                  ushort* __restrict__ xbc,
                                                  ushort* __restrict__ dtr) {
    constexpr int K = 2048, NT = 32;              // K-tiles of 64
    __shared__ ushort lds[2 * 28672];             // 112 KB: per buf A 16384 + B 12288
    const int tid = threadIdx.x, lane = tid & 63, wave = tid >> 6;
    const int wm = wave >> 2, wn = wave & 3;
    const int bid = blockIdx.x;
    const int xcd = bid & 7, w = bid >> 3;        // w in [0,92)
    const int mt = xcd * 2 + (w & 1), nt = w >> 1;
    const long m0 = (long)mt * 256, n0 = (long)nt * 192;

    const int st_row = lane >> 2;
    const int st_gc = ((lane & 3) * 8) ^ (((lane >> 5) & 1) << 4);

    auto STAGE_A = [&](int buf, int kt, int kb) {   // 2 loads/thread
#pragma unroll
        for (int j = 0; j < 2; j++) {
            int sidx = wave + j * 8;                // 16 subtiles of 16 rows
            gld16(A + (m0 + sidx * 16 + st_row) * K + kt + kb * 32 + st_gc,
                  lds + buf * 28672 + kb * 8192 + sidx * 512 + lane * 8);
        }
    };
    auto STAGE_B = [&](int buf, int kt, int kb) {   // 2|1 loads/thread
#pragma unroll
        for (int j = 0; j < 2; j++) {
            int sidx = wave + j * 8;                // 12 subtiles
            if (sidx < 12)
                gld16(Bm + (n0 + sidx * 16 + st_row) * K + kt + kb * 32 + st_gc,
                      lds + buf * 28672 + 16384 + kb * 6144 + sidx * 512 + lane * 8);
        }
    };

    const int cfr = (lane >> 4) * 8;
    const int lr = lane & 15;
    auto LDFA = [&](int buf, int r, int kb) -> s16x8 {
        int off = buf * 28672 + kb * 8192 + ((r >> 4) << 9) + ((r & 15) << 5)
                + (cfr ^ (((r >> 3) & 1) << 4));
        return *(const s16x8*)(lds + off);
    };
    auto LDFB = [&](int buf, int r, int kb) -> s16x8 {
        int off = buf * 28672 + 16384 + kb * 6144 + ((r >> 4) << 9) + ((r & 15) << 5)
                + (cfr ^ (((r >> 3) & 1) << 4));
        return *(const s16x8*)(lds + off);
    };

    f32x4 zero = { 0.f, 0.f, 0.f, 0.f };
    f32x4 acc[8][3];
#pragma unroll
    for (int i = 0; i < 8; i++)
#pragma unroll
        for (int j = 0; j < 3; j++) acc[i][j] = zero;

    // prologue: stage tile 0 fully into buf 0
    STAGE_A(0, 0, 0); STAGE_A(0, 0, 1);
    STAGE_B(0, 0, 0); STAGE_B(0, 0, 1);
    asm volatile("s_waitcnt vmcnt(0)" ::: "memory");
    BARRIER();

    for (int t = 0; t < NT; ++t) {
        const int cur = t & 1, nxt = cur ^ 1;
        const int ktn = (t + 1) * 64;
        const bool ds = (t + 1) < NT;

        s16x8 bfr[3][2];
        s16x8 aq[2][2];

        // ---- phase 0: B-frags + A quadrant 0 (mi 0,1); stage kb0 of t+1
#pragma unroll
        for (int ni = 0; ni < 3; ni++)
#pragma unroll
            for (int kk = 0; kk < 2; kk++)
                bfr[ni][kk] = LDFB(cur, wn * 48 + ni * 16 + lr, kk);
#pragma unroll
        for (int m2 = 0; m2 < 2; m2++)
#pragma unroll
            for (int kk = 0; kk < 2; kk++)
                aq[m2][kk] = LDFA(cur, wm * 128 + m2 * 16 + lr, kk);
        if (ds) { STAGE_A(nxt, ktn, 0); STAGE_B(nxt, ktn, 0); }
        BARRIER();
        __builtin_amdgcn_s_setprio(1);
#pragma unroll
        for (int m2 = 0; m2 < 2; m2++)
#pragma unroll
            for (int ni = 0; ni < 3; ni++)
#pragma unroll
                for (int kk = 0; kk < 2; kk++)
                    acc[m2][ni] = __builtin_amdgcn_mfma_f32_16x16x32_bf16(aq[m2][kk], bfr[ni][kk], acc[m2][ni], 0, 0, 0);
        __builtin_amdgcn_s_setprio(0);
        BARRIER();

        // ---- phase 1: A quadrant 1 (mi 2,3); stage kb1 of t+1
#pragma unroll
        for (int m2 = 0; m2 < 2; m2++)
#pragma unroll
            for (int kk = 0; kk < 2; kk++)
                aq[m2][kk] = LDFA(cur, wm * 128 + (2 + m2) * 16 + lr, kk);
        if (ds) { STAGE_A(nxt, ktn, 1); STAGE_B(nxt, ktn, 1); }
        BARRIER();
        __builtin_amdgcn_s_setprio(1);
#pragma unroll
        for (int m2 = 0; m2 < 2; m2++)
#pragma unroll
            for (int ni = 0; ni < 3; ni++)
#pragma unroll
                for (int kk = 0; kk < 2; kk++)
                    acc[2 + m2][ni] = __builtin_amdgcn_mfma_f32_16x16x32_bf16(aq[m2][kk], bfr[ni][kk], acc[2 + m2][ni], 0, 0, 0);
        __builtin_amdgcn_s_setprio(0);
        BARRIER();

        // ---- phase 2: A quadrant 2 (mi 4,5)
#pragma unroll
        for (int m2 = 0; m2 < 2; m2++)
#pragma unroll
            for (int kk = 0; kk < 2; kk++)
                aq[m2][kk] = LDFA(cur, wm * 128 + (4 + m2) * 16 + lr, kk);
        BARRIER();
        __builtin_amdgcn_s_setprio(1);
#pragma unroll
        for (int m2 = 0; m2 < 2; m2++)
#pragma unroll
            for (int ni = 0; ni < 3; ni++)
#pragma unroll
                for (int kk = 0; kk < 2; kk++)
                    acc[4 + m2][ni] = __builtin_amdgcn_mfma_f32_16x16x32_bf16(aq[m2][kk], bfr[ni][kk], acc[4 + m2][ni], 0, 0, 0);
        __builtin_amdgcn_s_setprio(0);
        BARRIER();

        // ---- phase 3: A quadrant 3 (mi 6,7); drain staging at tile end
#pragma unroll
        for (int m2 = 0; m2 < 2; m2++)
#pragma unroll
            for (int kk = 0; kk < 2; kk++)
                aq[m2][kk] = LDFA(cur, wm * 128 + (6 + m2) * 16 + lr, kk);
        BARRIER();
        __builtin_amdgcn_s_setprio(1);
#pragma unroll
        for (int m2 = 0; m2 < 2; m2++)
#pragma unroll
            for (int ni = 0; ni < 3; ni++)
#pragma unroll
                for (int kk = 0; kk < 2; kk++)
                    acc[6 + m2][ni] = __builtin_amdgcn_mfma_f32_16x16x32_bf16(aq[m2][kk], bfr[ni][kk], acc[6 + m2][ni], 0, 0, 0);
        __builtin_amdgcn_s_setprio(0);
        asm volatile("s_waitcnt vmcnt(0)" ::: "memory");
        BARRIER();
    }

    const int lr4 = (lane >> 4) * 4;
#pragma unroll
    for (int mi = 0; mi < 8; mi++) {
#pragma unroll
        for (int ni = 0; ni < 3; ni++) {
            const long col = n0 + wn * 48 + ni * 16 + lr;
            ushort* dst;
            long stride;
            if (col < 4096)      { dst = zbuf + col;         stride = 4096; }
            else if (col < 8448) { dst = xbc + (col - 4096); stride = 4352; }
            else if (col < 8480) { dst = dtr + (col - 8448); stride = 32;   }
            else continue;
            const long row0 = m0 + wm * 128 + mi * 16 + lr4;
#pragma unroll
            for (int r = 0; r < 4; r++) dst[(row0 + r) * stride] = f2bf(acc[mi][ni][r]);
        }
    }
}

// ---------------- GEMM2: 128x128 tile, BK=32, ring-2, grid 512 ------------
__global__ __launch_bounds__(256) void gemm2_k(const ushort* __restrict__ A,
                                               const ushort* __restrict__ Bm,
                                               float* __restrict__ Cout) {
    constexpr int K = 4096, NT = 128;
    __shared__ ushort lds[2 * 4096 + 2 * 4096];   // 32 KB
    const int tid = threadIdx.x, lane = tid & 63, wave = tid >> 6;
    const int wm = wave >> 1, wn = wave & 1;
    const int bid = blockIdx.x;                    // 512 = 8 x (4 mt x 16 nt)
    const int xcd = bid & 7, w = bid >> 3;
    const int mt = xcd * 4 + (w & 3), nt = w >> 2;
    const long m0 = (long)mt * 128, n0 = (long)nt * 128;

    const int st_row = lane >> 2;
    const int st_gc = ((lane & 3) * 8) ^ (((lane >> 5) & 1) << 4);

    auto STAGE = [&](int buf, int kt) {
#pragma unroll
        for (int j = 0; j < 2; j++) {
            int sidx = wave + j * 4;               // 8 subtiles (128 rows)
            gld16(A + (m0 + sidx * 16 + st_row) * K + kt + st_gc,
                  lds + buf * 4096 + sidx * 512 + lane * 8);
        }
#pragma unroll
        for (int j = 0; j < 2; j++) {
            int sidx = wave + j * 4;
            gld16(Bm + (n0 + sidx * 16 + st_row) * K + kt + st_gc,
                  lds + 8192 + buf * 4096 + sidx * 512 + lane * 8);
        }
    };

    const int cfr = (lane >> 4) * 8;
    const int lr = lane & 15;
    auto LDFA = [&](int buf, int r) -> s16x8 {
        int off = buf * 4096 + ((r >> 4) << 9) + ((r & 15) << 5)
                + (cfr ^ (((r >> 3) & 1) << 4));
        return *(const s16x8*)(lds + off);
    };
    auto LDFB = [&](int buf, int r) -> s16x8 {
        int off = 8192 + buf * 4096 + ((r >> 4) << 9) + ((r & 15) << 5)
                + (cfr ^ (((r >> 3) & 1) << 4));
        return *(const s16x8*)(lds + off);
    };

    f32x4 zero = { 0.f, 0.f, 0.f, 0.f };
    f32x4 acc[4][4];
#pragma unroll
    for (int i = 0; i < 4; i++)
#pragma unroll
        for (int j = 0; j < 4; j++) acc[i][j] = zero;

    STAGE(0, 0);
    asm volatile("s_waitcnt vmcnt(0)" ::: "memory");
    BARRIER();

    for (int t = 0; t < NT; ++t) {
        const int cur = t & 1;
        if ((t + 1) < NT) STAGE((t + 1) & 1, (t + 1) * 32);

        s16x8 af[4], bf[4];
#pragma unroll
        for (int mi = 0; mi < 4; mi++) af[mi] = LDFA(cur, wm * 64 + mi * 16 + lr);
#pragma unroll
        for (int ni = 0; ni < 4; ni++) bf[ni] = LDFB(cur, wn * 64 + ni * 16 + lr);

        __builtin_amdgcn_s_setprio(1);
#pragma unroll
        for (int mi = 0; mi < 4; mi++)
#pragma unroll
            for (int ni = 0; ni < 4; ni++)
                acc[mi][ni] = __builtin_amdgcn_mfma_f32_16x16x32_bf16(af[mi], bf[ni], acc[mi][ni], 0, 0, 0);
        __builtin_amdgcn_s_setprio(0);

        asm volatile("s_waitcnt vmcnt(0)" ::: "memory");
        BARRIER();
    }

    const long crow = m0 + wm * 64 + ((lane >> 4) << 2);
    const long ccol = n0 + wn * 64 + (lane & 15);
#pragma unroll
    for (int mi = 0; mi < 4; mi++)
#pragma unroll
        for (int ni = 0; ni < 4; ni++)
#pragma unroll
            for (int r = 0; r < 4; r++)
                Cout[(crow + mi * 16 + r) * 2048 + ccol + ni * 16] = acc[mi][ni][r];
}

// ---------------- fused causal conv (K=4) + SiLU + transpose ----------------
__global__ __launch_bounds__(256) void convx_k(const ushort* __restrict__ xbc,
                                               const float* __restrict__ w,
                                               const float* __restrict__ bias,
                                               ushort* __restrict__ xbcc,
                                               ushort* __restrict__ xT,
                                               ushort* __restrict__ Bt) {
    __shared__ ushort xin[35][136];
    __shared__ ushort yL[32][132];
    const int stile = blockIdx.x, slot = blockIdx.y, bc = blockIdx.z;
    const int tid = threadIdx.x;
    const int cc = bc & 7;
    const long tbase = (long)bc * 256 + stile * 32;
    const int c0 = slot * 128;
    const bool head = (cc == 0 && stile == 0);

#pragma unroll
    for (int i = 0; i < 3; i++) {
        int u = tid + i * 256;
        if (u < 560) {
            int r = u >> 4, seg = u & 15;
            s16x8 v;
            if (head && r < 3) {
#pragma unroll
                for (int j = 0; j < 8; j++) v[j] = 0;
            } else {
                v = *(const s16x8*)&xbc[(tbase - 3 + r) * 4352 + c0 + seg * 8];
            }
            *(s16x8*)&xin[r][seg * 8] = v;
        }
    }
    __syncthreads();

    const int s_loc = tid >> 3, p0 = (tid & 7) * 16;
    ushort yo[16];
#pragma unroll
    for (int j = 0; j < 16; j++) {
        int c = p0 + j;
        float a = bias[c0 + c];
#pragma unroll
        for (int k = 0; k < 4; k++)
            a += bf2f(xin[s_loc + k][c]) * w[(c0 + c) * 4 + k];
        float yv = a / (1.f + __expf(-a));
        ushort ub = f2bf(yv);
        yo[j] = ub;
        yL[s_loc][c] = ub;
    }
    *(s16x8*)&xbcc[(tbase + s_loc) * 4352 + c0 + p0] = *(const s16x8*)&yo[0];
    *(s16x8*)&xbcc[(tbase + s_loc) * 4352 + c0 + p0 + 8] = *(const s16x8*)&yo[8];
    __syncthreads();

    if (slot < 33) {
        const int p = tid >> 1, s0 = (tid & 1) * 16;
        ushort o[16];
#pragma unroll
        for (int j = 0; j < 16; j++) o[j] = yL[s0 + j][p];
        ushort* dst = (slot < 32)
            ? (xT + ((long)(bc * 32 + slot) * 128 + p) * 256 + stile * 32 + s0)
            : (Bt + ((long)bc * 128 + p) * 256 + stile * 32 + s0);
        *(s16x8*)&dst[0] = *(const s16x8*)&o[0];
        *(s16x8*)&dst[8] = *(const s16x8*)&o[8];
    }
}

// ---------------- dt softplus/clip + per-chunk cumsum ----------------
__global__ void prep_k(const ushort* __restrict__ dtr, const float* __restrict__ dt_bias,
                       const float* __restrict__ A_log, float* __restrict__ dtp,
                       float* __restrict__ dacs) {
    const int bx = blockIdx.x;
    const int h = bx & 31, cc = (bx >> 5) & 7, bi = bx >> 8;
    const int lane = threadIdx.x;
    const float A = -__expf(A_log[h]);
    const float bsh = dt_bias[h];
    float v[4], cs[4];
    float run = 0.f;
#pragma unroll
    for (int j = 0; j < 4; j++) {
        int pos = cc * 256 + lane * 4 + j;
        float raw = bf2f(dtr[((long)(bi * 2048 + pos)) * 32 + h]) + bsh;
        float sp = (raw > 20.f) ? raw : log1pf(__expf(raw));
        float d = fminf(fmaxf(sp, 0.001f), 0.1f);
        v[j] = d;
        run += d * A;
        cs[j] = run;
    }
    float tot = run, pre = run;
    for (int off = 1; off < 64; off <<= 1) {
        float u = __shfl_up(pre, off, 64);
        if (lane >= off) pre += u;
    }
    float excl = pre - tot;
    const long base = ((long)(bi * 32 + h)) * 2048 + cc * 256 + lane * 4;
#pragma unroll
    for (int j = 0; j < 4; j++) { dtp[base + j] = v[j]; dacs[base + j] = excl + cs[j]; }
}

// ---------------- CB = C.B^T per chunk via MFMA ----------------
__global__ __launch_bounds__(256) void cb_mfma_k(const ushort* __restrict__ xbcc,
                                                 float* __restrict__ CB) {
    const int bid = blockIdx.x;
    const int sq = bid & 1, lq = (bid >> 1) & 1, bc = bid >> 2;
    const int tid = threadIdx.x, lane = tid & 63, wave = tid >> 6;
    const int wm = wave >> 1, wn = wave & 1;
    const long tbase = (long)bc * 256;

    f32x4 zero = { 0.f, 0.f, 0.f, 0.f };
    f32x4 acc[4][4];
#pragma unroll
    for (int i = 0; i < 4; i++)
#pragma unroll
        for (int j = 0; j < 4; j++) acc[i][j] = zero;

    for (int kst = 0; kst < 4; ++kst) {
        const int koff = kst * 32 + (lane >> 4) * 8;
        s16x8 a[4], b[4];
#pragma unroll
        for (int mi = 0; mi < 4; mi++) {
            int l = lq * 128 + wm * 64 + mi * 16 + (lane & 15);
            a[mi] = *(const s16x8*)&xbcc[(tbase + l) * 4352 + 4224 + koff];
        }
#pragma unroll
        for (int ni = 0; ni < 4; ni++) {
            int s = sq * 128 + wn * 64 + ni * 16 + (lane & 15);
            b[ni] = *(const s16x8*)&xbcc[(tbase + s) * 4352 + 4096 + koff];
        }
#pragma unroll
        for (int mi = 0; mi < 4; mi++)
#pragma unroll
            for (int ni = 0; ni < 4; ni++)
                acc[mi][ni] = __builtin_amdgcn_mfma_f32_16x16x32_bf16(a[mi], b[ni], acc[mi][ni], 0, 0, 0);
    }

    float* out = CB + (long)bc * 65536;
#pragma unroll
    for (int mi = 0; mi < 4; mi++)
#pragma unroll
        for (int ni = 0; ni < 4; ni++)
#pragma unroll
            for (int r = 0; r < 4; r++) {
                int l = lq * 128 + wm * 64 + mi * 16 + (lane >> 4) * 4 + r;
                int s = sq * 128 + wn * 64 + ni * 16 + (lane & 15);
                out[(long)l * 256 + s] = acc[mi][ni][r];
            }
}

// ---------------- fused intra+inter scan via MFMA (single bf16 write) ------
__global__ __launch_bounds__(256) void scan_mfma_k(const ushort* __restrict__ xT,
                                                   const float* __restrict__ CB,
                                                   const float* __restrict__ dtp,
                                                   const float* __restrict__ dacs,
                                                   const ushort* __restrict__ xbcc,
                                                   const float* __restrict__ st,
                                                   ushort* __restrict__ yh) {
    const int bx = blockIdx.x;
    const int ltile = bx & 1, h = (bx >> 1) & 31, cc = (bx >> 6) & 7, bi = bx >> 9;
    const int tid = threadIdx.x, lane = tid & 63, wave = tid >> 6;
    const int wm = wave >> 1, wn = wave & 1;

    __shared__ float dA_s[256];
    __shared__ float F_s[256];

    const long dbase = ((long)(bi * 32 + h)) * 2048 + cc * 256;
    {
        float a = dacs[dbase + tid];
        float r = dacs[dbase + (tid | 31)];
        dA_s[tid] = a;
        F_s[tid] = __expf(r - a) * dtp[dbase + tid];
    }
    __syncthreads();

    int lch[4];
    float dAl[4];
#pragma unroll
    for (int mi = 0; mi < 4; mi++) {
        lch[mi] = ltile * 128 + wm * 64 + mi * 16 + (lane & 15);
        dAl[mi] = dA_s[lch[mi]];
    }

    f32x4 zero = { 0.f, 0.f, 0.f, 0.f };
    f32x4 acc[4][4];
#pragma unroll
    for (int i = 0; i < 4; i++)
#pragma unroll
        for (int j = 0; j < 4; j++) acc[i][j] = zero;

    const long tbase = (long)bi * 2048 + cc * 256;
    const long cbbase = ((long)(bi * 8 + cc)) * 65536;
    const ushort* xrow = xT + (((long)(bi * 8 + cc) * 32 + h) * 128) * 256;
    const int nsb = ltile * 4 + 4;

    for (int sb = 0; sb < nsb; ++sb) {
        const int soff = sb * 32 + (lane >> 4) * 8;
        s16x8 bf[4];
#pragma unroll
        for (int ni = 0; ni < 4; ni++) {
            int p = wn * 64 + ni * 16 + (lane & 15);
            bf[ni] = *(const s16x8*)&xrow[(long)p * 256 + soff];
        }
        const float Rsb = dA_s[sb * 32 + 31];
        const int s0 = soff;
#pragma unroll
        for (int mi = 0; mi < 4; mi++) {
            const int lb = lch[mi] >> 5;
            if (sb > lb) continue;
            const float* cbrow = CB + cbbase + (long)lch[mi] * 256 + s0;
            float4 c0 = *(const float4*)cbrow;
            float4 c1 = *(const float4*)(cbrow + 4);
            float E = __expf(dAl[mi] - Rsb);
            float m[8];
            m[0] = c0.x * E * F_s[s0 + 0]; m[1] = c0.y * E * F_s[s0 + 1];
            m[2] = c0.z * E * F_s[s0 + 2]; m[3] = c0.w * E * F_s[s0 + 3];
            m[4] = c1.x * E * F_s[s0 + 4]; m[5] = c1.y * E * F_s[s0 + 5];
            m[6] = c1.z * E * F_s[s0 + 6]; m[7] = c1.w * E * F_s[s0 + 7];
            if (sb == lb) {
#pragma unroll
                for (int j = 0; j < 8; j++)
                    if (s0 + j > lch[mi]) m[j] = 0.f;
            }
            s16x8 a;
#pragma unroll
            for (int j = 0; j < 8; j++) a[j] = (short)f2bf(m[j]);
#pragma unroll
            for (int ni = 0; ni < 4; ni++)
                acc[mi][ni] = __builtin_amdgcn_mfma_f32_16x16x32_bf16(a, bf[ni], acc[mi][ni], 0, 0, 0);
        }
    }

    const float* sbase = st + (((long)(bi * 8 + cc) * 32 + h) * 128) * 128;
    float eAr[4];
#pragma unroll
    for (int mi = 0; mi < 4; mi++) eAr[mi] = __expf(dAl[mi]);
    for (int kk = 0; kk < 4; ++kk) {
        const int koff = kk * 32 + (lane >> 4) * 8;
        s16x8 a[4], b[4];
#pragma unroll
        for (int mi = 0; mi < 4; mi++) {
            s16x8 raw = *(const s16x8*)&xbcc[(tbase + lch[mi]) * 4352 + 4224 + koff];
#pragma unroll
            for (int j = 0; j < 8; j++)
                a[mi][j] = (short)f2bf(bf2f((ushort)raw[j]) * eAr[mi]);
        }
#pragma unroll
        for (int ni = 0; ni < 4; ni++) {
            int p = wn * 64 + ni * 16 + (lane & 15);
            const float* pr = sbase + (long)p * 128 + koff;
            float4 v0 = *(const float4*)pr;
            float4 v1 = *(const float4*)(pr + 4);
            b[ni][0] = (short)f2bf(v0.x); b[ni][1] = (short)f2bf(v0.y);
            b[ni][2] = (short)f2bf(v0.z); b[ni][3] = (short)f2bf(v0.w);
            b[ni][4] = (short)f2bf(v1.x); b[ni][5] = (short)f2bf(v1.y);
            b[ni][6] = (short)f2bf(v1.z); b[ni][7] = (short)f2bf(v1.w);
        }
#pragma unroll
        for (int mi = 0; mi < 4; mi++)
#pragma unroll
            for (int ni = 0; ni < 4; ni++)
                acc[mi][ni] = __builtin_amdgcn_mfma_f32_16x16x32_bf16(a[mi], b[ni], acc[mi][ni], 0, 0, 0);
    }

    const long crow = tbase + ltile * 128 + wm * 64 + ((lane >> 4) << 2);
    const int ccol = h * 128 + wn * 64 + (lane & 15);
#pragma unroll
    for (int mi = 0; mi < 4; mi++)
#pragma unroll
        for (int ni = 0; ni < 4; ni++)
#pragma unroll
            for (int r = 0; r < 4; r++)
                yh[(crow + mi * 16 + r) * 4096 + ccol + ni * 16] = f2bf(acc[mi][ni][r]);
}

// ---------------- per-chunk end states via MFMA ----------------
__global__ __launch_bounds__(256) void states_mfma_k(const ushort* __restrict__ xT,
                                                     const ushort* __restrict__ Bt,
                                                     const float* __restrict__ dtp,
                                                     const float* __restrict__ dacs,
                                                     float* __restrict__ states) {
    const int bx = blockIdx.x;
    const int h = bx & 31, cc = (bx >> 5) & 7, bi = bx >> 8;
    const int bc = bi * 8 + cc;
    const int tid = threadIdx.x, lane = tid & 63, wave = tid >> 6;
    const int wm = wave >> 1, wn = wave & 1;
    __shared__ float wl[256];
    const long dbase = ((long)(bi * 32 + h)) * 2048 + cc * 256;
    {
        float last = dacs[dbase + 255];
        wl[tid] = __expf(last - dacs[dbase + tid]) * dtp[dbase + tid];
    }
    __syncthreads();

    f32x4 zero = { 0.f, 0.f, 0.f, 0.f };
    f32x4 acc[4][4];
#pragma unroll
    for (int i = 0; i < 4; i++)
#pragma unroll
        for (int j = 0; j < 4; j++) acc[i][j] = zero;

    const ushort* xrow = xT + (((long)bc * 32 + h) * 128) * 256;
    const ushort* brow = Bt + ((long)bc * 128) * 256;

    for (int sb = 0; sb < 8; ++sb) {
        const int soff = sb * 32 + (lane >> 4) * 8;
        s16x8 a[4], b[4];
#pragma unroll
        for (int mi = 0; mi < 4; mi++) {
            int p = wm * 64 + mi * 16 + (lane & 15);
            s16x8 raw = *(const s16x8*)&xrow[(long)p * 256 + soff];
#pragma unroll
            for (int j = 0; j < 8; j++)
                a[mi][j] = (short)f2bf(bf2f((ushort)raw[j]) * wl[soff + j]);
        }
#pragma unroll
        for (int ni = 0; ni < 4; ni++) {
            int n = wn * 64 + ni * 16 + (lane & 15);
            b[ni] = *(const s16x8*)&brow[(long)n * 256 + soff];
        }
#pragma unroll
        for (int mi = 0; mi < 4; mi++)
#pragma unroll
            for (int ni = 0; ni < 4; ni++)
                acc[mi][ni] = __builtin_amdgcn_mfma_f32_16x16x32_bf16(a[mi], b[ni], acc[mi][ni], 0, 0, 0);
    }

    float* out = states + (((long)bc * 32 + h) * 128) * 128;
#pragma unroll
    for (int mi = 0; mi < 4; mi++)
#pragma unroll
        for (int ni = 0; ni < 4; ni++)
#pragma unroll
            for (int r = 0; r < 4; r++) {
                int p = wm * 64 + mi * 16 + (lane >> 4) * 4 + r;
                int n = wn * 64 + ni * 16 + (lane & 15);
                out[(long)p * 128 + n] = acc[mi][ni][r];
            }
}

// ---------------- chunk recurrence: states -> prev_states (in place) ----------------
__global__ void rec_k(float* __restrict__ states, const float* __restrict__ dacs) {
    const int i = blockIdx.x * 256 + threadIdx.x;
    const int n = i & 127, p = (i >> 7) & 127, h = (i >> 14) & 31, bi = i >> 19;
    const long dbase = ((long)(bi * 32 + h)) * 2048;
    float run = 0.f;
    for (int cc = 0; cc < 8; cc++) {
        const long off = ((((long)(bi * 8 + cc)) * 32 + h) * 128 + p) * 128 + n;
        float st = states[off];
        states[off] = run;
        float dec = dacs[dbase + cc * 256 + 255];
        run = run * __expf(dec) + st;
    }
}

// ---------------- gate (silu(z)) + D*x + RMSNorm -> bf16 ----------------
__global__ __launch_bounds__(256) void gate_rms_k(const ushort* __restrict__ yh, const ushort* __restrict__ zbuf,
                                                  const ushort* __restrict__ xbcc, const float* __restrict__ Dv,
                                                  const float* __restrict__ norm_w, ushort* __restrict__ yb) {
    const int t = blockIdx.x, tid = threadIdx.x;
    const ushort* yr = &yh[(long)t * 4096];
    const ushort* zr = &zbuf[(long)t * 4096];
    const ushort* xr = &xbcc[(long)t * 4352];
    float g[16];
    float ss = 0.f;
#pragma unroll
    for (int j = 0; j < 16; j++) {
        int i = j * 256 + tid;
        float z = bf2f(zr[i]);
        float yv = bf2f(yr[i]) + Dv[i >> 7] * bf2f(xr[i]);
        float gv = yv * (z / (1.f + __expf(-z)));
        g[j] = gv;
        ss += gv * gv;
    }
#pragma unroll
    for (int off = 32; off > 0; off >>= 1) ss += __shfl_xor(ss, off, 64);
    __shared__ float red[4];
    if ((tid & 63) == 0) red[tid >> 6] = ss;
    __syncthreads();
    float tot = red[0] + red[1] + red[2] + red[3];
    float sc = rsqrtf(tot * (1.f / 4096.f) + 1e-6f);
#pragma unroll
    for (int j = 0; j < 16; j++) {
        int i = j * 256 + tid;
        yb[(long)t * 4096 + i] = f2bf(g[j] * sc * norm_w[i]);
    }
}

// ---------------------------------------------------------------------------
extern "C" void kernel_launch(void* const* d_in, const int* in_sizes, int n_in,
                              void* d_out, int out_size, void* d_ws, size_t ws_size,
                              hipStream_t stream) {
    const float* x       = (const float*)d_in[0];
    const float* W_in    = (const float*)d_in[1];
    const float* conv_w  = (const float*)d_in[2];
    const float* conv_b  = (const float*)d_in[3];
    const float* dt_bias = (const float*)d_in[4];
    const float* A_log   = (const float*)d_in[5];
    const float* Dv      = (const float*)d_in[6];
    const float* norm_w  = (const float*)d_in[7];
    const float* W_out   = (const float*)d_in[8];

    char* w8 = (char*)d_ws;
    ushort* xb    = (ushort*)(w8 + 0L);
    ushort* xT    = (ushort*)(w8 + 0L);            // alias (xb dead after GEMM1)
    ushort* yb    = (ushort*)(w8 + 0L);            // alias (xT dead before gate)
    ushort* woutb = (ushort*)(w8 + 33554432L);
    ushort* Bt    = (ushort*)(w8 + 50331648L);
    ushort* zbuf  = (ushort*)(w8 + 52428800L);
    ushort* xbc   = (ushort*)(w8 + 85983232L);
    ushort* dtr   = (ushort*)(w8 + 121634816L);
    ushort* xbcc  = (ushort*)(w8 + 121896960L);
    float*  dtp   = (float*)(w8 + 157548544L);
    float*  dacs  = (float*)(w8 + 158072832L);
    float*  cb    = (float*)(w8 + 158597120L);
    ushort* yh    = (ushort*)(w8 + 162791424L);    // bf16 scan output
    ushort* winb  = (ushort*)(w8 + 162791424L);    // alias (dead before yh written)
    float*  st    = (float*)(w8 + 229900288L);

    cast_all_k<<<34048, 256, 0, stream>>>((const float4*)x, (const float4*)W_out,
                                          (const float4*)W_in, xb, woutb, winb);
    gemm1_k<<<736, 512, 0, stream>>>(xb, winb, zbuf, xbc, dtr);
    convx_k<<<dim3(8, 34, 16), 256, 0, stream>>>(xbc, conv_w, conv_b, xbcc, xT, Bt);
    prep_k<<<512, 64, 0, stream>>>(dtr, dt_bias, A_log, dtp, dacs);
    cb_mfma_k<<<64, 256, 0, stream>>>(xbcc, cb);
    states_mfma_k<<<512, 256, 0, stream>>>(xT, Bt, dtp, dacs, st);
    rec_k<<<4096, 256, 0, stream>>>(st, dacs);
    scan_mfma_k<<<1024, 256, 0, stream>>>(xT, cb, dtp, dacs, xbcc, st, yh);
    gate_rms_k<<<4096, 256, 0, stream>>>(yh, zbuf, xbcc, Dv, norm_w, yb);
    gemm2_k<<<512, 256, 0, stream>>>(yb, woutb, (float*)d_out);
}

// Round 15
// 446.206 us; speedup vs baseline: 2.4222x; 1.0291x over previous
//
#include <hip/hip_runtime.h>

// ---------------------------------------------------------------------------
// SSM (Mamba2-style) fused forward for MI355X.
// R15: dispatch consolidation on top of R13 (best: 459us, absmax 0.03125).
//      - gemm1 = R13 ring-3 1-barrier (best measured; BK=64 4-phase variant
//        falsified at 177-182us -> reverted).
//      - prep merged into convx (slot==34 blocks, 4 waves x 1 unit each).
//      - cb merged into states (blocks >= 512 do cb work).
//      10 -> 8 dispatches; no math changes.
// ws layout (bytes): unchanged.
// ---------------------------------------------------------------------------

typedef short s16x8 __attribute__((ext_vector_type(8)));
typedef float f32x4 __attribute__((ext_vector_type(4)));

__device__ __forceinline__ float bf2f(ushort u) {
    return __builtin_bit_cast(float, (unsigned)u << 16);
}
__device__ __forceinline__ ushort f2bf(float f) {
    unsigned u = __builtin_bit_cast(unsigned, f);
    unsigned r = u + 0x7fffu + ((u >> 16) & 1u);
    return (ushort)(r >> 16);
}

__device__ __forceinline__ void gld16(const void* g, void* l) {
    __builtin_amdgcn_global_load_lds((__attribute__((address_space(1))) void*)g,
                                     (__attribute__((address_space(3))) void*)l, 16, 0, 0);
}

#define BARRIER() asm volatile("s_barrier" ::: "memory")

// ---------------- unified cast kernel ----------------
__global__ void cast_all_k(const float4* __restrict__ x, const float4* __restrict__ wout,
                           const float4* __restrict__ win, ushort* __restrict__ xb,
                           ushort* __restrict__ woutb, ushort* __restrict__ winb) {
    const long b = blockIdx.x, tid = threadIdx.x;
    if (b < 8192) {
        long i = b * 256 + tid;
        float4 v = x[i];
        ushort4 o = { f2bf(v.x), f2bf(v.y), f2bf(v.z), f2bf(v.w) };
        *(ushort4*)(xb + i * 4) = o;
    } else if (b < 16384) {
        long i = (b - 8192) * 256 + tid;
        float4 v = wout[i];
        ushort4 o = { f2bf(v.x), f2bf(v.y), f2bf(v.z), f2bf(v.w) };
        *(ushort4*)(woutb + i * 4) = o;
    } else {
        long i = (b - 16384) * 256 + tid;   // < 8832*2048/4
        ushort4 o;
        if (i < 4341760L) {                 // 8480*2048/4
            float4 v = win[i];
            o = { f2bf(v.x), f2bf(v.y), f2bf(v.z), f2bf(v.w) };
        } else {
            o = { 0, 0, 0, 0 };
        }
        *(ushort4*)(winb + i * 4) = o;
    }
}

// ---------------- GEMM1: 256x192 tile, BK=32, 3-ring, 1 barrier/K-tile ----
__global__ __launch_bounds__(512, 1) void gemm1_k(const ushort* __restrict__ A,
                                                  const ushort* __restrict__ Bm,
                                                  ushort* __restrict__ zbuf,
                                                  ushort* __restrict__ xbc,
                                                  ushort* __restrict__ dtr) {
    constexpr int K = 2048, NT = 64;
    __shared__ ushort lds[3 * 8192 + 3 * 6144];
    const int tid = threadIdx.x, lane = tid & 63, wave = tid >> 6;
    const int wm = wave >> 2, wn = wave & 3;
    const int bid = blockIdx.x;
    const int xcd = bid & 7, w = bid >> 3;      // w in [0,92)
    const int mt = xcd * 2 + (w & 1), nt = w >> 1;
    const long m0 = (long)mt * 256, n0 = (long)nt * 192;

    const int st_row = lane >> 2;
    const int st_gc = ((lane & 3) * 8) ^ (((lane >> 5) & 1) << 4);

    auto STAGE_A = [&](int buf, int kt) {
#pragma unroll
        for (int j = 0; j < 2; j++) {
            int sidx = wave + j * 8;
            gld16(A + (m0 + sidx * 16 + st_row) * K + kt + st_gc,
                  lds + buf * 8192 + sidx * 512 + lane * 8);
        }
    };
    auto STAGE_B = [&](int buf, int kt) {
#pragma unroll
        for (int j = 0; j < 2; j++) {
            int sidx = wave + j * 8;
            if (sidx < 12)
                gld16(Bm + (n0 + sidx * 16 + st_row) * K + kt + st_gc,
                      lds + 24576 + buf * 6144 + sidx * 512 + lane * 8);
        }
    };

    const int cfr = (lane >> 4) * 8;
    const int lr = lane & 15;
    auto LDFA = [&](int buf, int r) -> s16x8 {
        int off = buf * 8192 + ((r >> 4) << 9) + ((r & 15) << 5)
                + (cfr ^ (((r >> 3) & 1) << 4));
        return *(const s16x8*)(lds + off);
    };
    auto LDFB = [&](int buf, int r) -> s16x8 {
        int off = 24576 + buf * 6144 + ((r >> 4) << 9) + ((r & 15) << 5)
                + (cfr ^ (((r >> 3) & 1) << 4));
        return *(const s16x8*)(lds + off);
    };

    f32x4 zero = { 0.f, 0.f, 0.f, 0.f };
    f32x4 acc[8][3];
#pragma unroll
    for (int i = 0; i < 8; i++)
#pragma unroll
        for (int j = 0; j < 3; j++) acc[i][j] = zero;

    STAGE_A(0, 0);  STAGE_B(0, 0);
    STAGE_A(1, 32); STAGE_B(1, 32);
    asm volatile("s_waitcnt vmcnt(3)" ::: "memory");
    BARRIER();

    for (int t = 0; t < NT; ++t) {
        const int cur = t % 3;
        const int nxt = (t + 2) % 3;
        const int kt2 = (t + 2) * 32;
        const bool do_stage = (t + 2) < NT;

        s16x8 bfr[3], alo[4], ahi[4];
#pragma unroll
        for (int ni = 0; ni < 3; ni++) bfr[ni] = LDFB(cur, wn * 48 + ni * 16 + lr);
#pragma unroll
        for (int mi = 0; mi < 4; mi++) alo[mi] = LDFA(cur, wm * 128 + mi * 16 + lr);
#pragma unroll
        for (int mi = 0; mi < 4; mi++) ahi[mi] = LDFA(cur, wm * 128 + 64 + mi * 16 + lr);
        if (do_stage) { STAGE_A(nxt, kt2); STAGE_B(nxt, kt2); }

        __builtin_amdgcn_s_setprio(1);
#pragma unroll
        for (int mi = 0; mi < 4; mi++)
#pragma unroll
            for (int ni = 0; ni < 3; ni++)
                acc[mi][ni] = __builtin_amdgcn_mfma_f32_16x16x32_bf16(alo[mi], bfr[ni], acc[mi][ni], 0, 0, 0);
#pragma unroll
        for (int mi = 0; mi < 4; mi++)
#pragma unroll
            for (int ni = 0; ni < 3; ni++)
                acc[mi + 4][ni] = __builtin_amdgcn_mfma_f32_16x16x32_bf16(ahi[mi], bfr[ni], acc[mi + 4][ni], 0, 0, 0);
        __builtin_amdgcn_s_setprio(0);

        if (do_stage) asm volatile("s_waitcnt vmcnt(3)" ::: "memory");
        else          asm volatile("s_waitcnt vmcnt(0)" ::: "memory");
        BARRIER();
    }

    const int lr4 = (lane >> 4) * 4;
#pragma unroll
    for (int mi = 0; mi < 8; mi++) {
#pragma unroll
        for (int ni = 0; ni < 3; ni++) {
            const long col = n0 + wn * 48 + ni * 16 + lr;
            ushort* dst;
            long stride;
            if (col < 4096)      { dst = zbuf + col;         stride = 4096; }
            else if (col < 8448) { dst = xbc + (col - 4096); stride = 4352; }
            else if (col < 8480) { dst = dtr + (col - 8448); stride = 32;   }
            else continue;
            const long row0 = m0 + wm * 128 + mi * 16 + lr4;
#pragma unroll
            for (int r = 0; r < 4; r++) dst[(row0 + r) * stride] = f2bf(acc[mi][ni][r]);
        }
    }
}

// ---------------- GEMM2: 128x128 tile, BK=32, ring-2, grid 512 ------------
__global__ __launch_bounds__(256) void gemm2_k(const ushort* __restrict__ A,
                                               const ushort* __restrict__ Bm,
                                               float* __restrict__ Cout) {
    constexpr int K = 4096, NT = 128;
    __shared__ ushort lds[2 * 4096 + 2 * 4096];   // 32 KB
    const int tid = threadIdx.x, lane = tid & 63, wave = tid >> 6;
    const int wm = wave >> 1, wn = wave & 1;
    const int bid = blockIdx.x;                    // 512 = 8 x (4 mt x 16 nt)
    const int xcd = bid & 7, w = bid >> 3;
    const int mt = xcd * 4 + (w & 3), nt = w >> 2;
    const long m0 = (long)mt * 128, n0 = (long)nt * 128;

    const int st_row = lane >> 2;
    const int st_gc = ((lane & 3) * 8) ^ (((lane >> 5) & 1) << 4);

    auto STAGE = [&](int buf, int kt) {
#pragma unroll
        for (int j = 0; j < 2; j++) {
            int sidx = wave + j * 4;               // 8 subtiles (128 rows)
            gld16(A + (m0 + sidx * 16 + st_row) * K + kt + st_gc,
                  lds + buf * 4096 + sidx * 512 + lane * 8);
        }
#pragma unroll
        for (int j = 0; j < 2; j++) {
            int sidx = wave + j * 4;
            gld16(Bm + (n0 + sidx * 16 + st_row) * K + kt + st_gc,
                  lds + 8192 + buf * 4096 + sidx * 512 + lane * 8);
        }
    };

    const int cfr = (lane >> 4) * 8;
    const int lr = lane & 15;
    auto LDFA = [&](int buf, int r) -> s16x8 {
        int off = buf * 4096 + ((r >> 4) << 9) + ((r & 15) << 5)
                + (cfr ^ (((r >> 3) & 1) << 4));
        return *(const s16x8*)(lds + off);
    };
    auto LDFB = [&](int buf, int r) -> s16x8 {
        int off = 8192 + buf * 4096 + ((r >> 4) << 9) + ((r & 15) << 5)
                + (cfr ^ (((r >> 3) & 1) << 4));
        return *(const s16x8*)(lds + off);
    };

    f32x4 zero = { 0.f, 0.f, 0.f, 0.f };
    f32x4 acc[4][4];
#pragma unroll
    for (int i = 0; i < 4; i++)
#pragma unroll
        for (int j = 0; j < 4; j++) acc[i][j] = zero;

    STAGE(0, 0);
    asm volatile("s_waitcnt vmcnt(0)" ::: "memory");
    BARRIER();

    for (int t = 0; t < NT; ++t) {
        const int cur = t & 1;
        if ((t + 1) < NT) STAGE((t + 1) & 1, (t + 1) * 32);

        s16x8 af[4], bf[4];
#pragma unroll
        for (int mi = 0; mi < 4; mi++) af[mi] = LDFA(cur, wm * 64 + mi * 16 + lr);
#pragma unroll
        for (int ni = 0; ni < 4; ni++) bf[ni] = LDFB(cur, wn * 64 + ni * 16 + lr);

        __builtin_amdgcn_s_setprio(1);
#pragma unroll
        for (int mi = 0; mi < 4; mi++)
#pragma unroll
            for (int ni = 0; ni < 4; ni++)
                acc[mi][ni] = __builtin_amdgcn_mfma_f32_16x16x32_bf16(af[mi], bf[ni], acc[mi][ni], 0, 0, 0);
        __builtin_amdgcn_s_setprio(0);

        asm volatile("s_waitcnt vmcnt(0)" ::: "memory");
        BARRIER();
    }

    const long crow = m0 + wm * 64 + ((lane >> 4) << 2);
    const long ccol = n0 + wn * 64 + (lane & 15);
#pragma unroll
    for (int mi = 0; mi < 4; mi++)
#pragma unroll
        for (int ni = 0; ni < 4; ni++)
#pragma unroll
            for (int r = 0; r < 4; r++)
                Cout[(crow + mi * 16 + r) * 2048 + ccol + ni * 16] = acc[mi][ni][r];
}

// ---------------- fused conv+SiLU+transpose AND dt-prep (slot==34) --------
// grid dim3(8, 35, 16), 256 thr.
// slot<34: conv channels [slot*128, slot*128+128) for 32 tokens; transpose
//          to xT (slot<32) / Bt (slot==32).
// slot==34: dt softplus/clip + per-chunk cumsum; unit g=(bc*8+stile)*4+wave.
__global__ __launch_bounds__(256) void convx_prep_k(const ushort* __restrict__ xbc,
                                                    const float* __restrict__ w,
                                                    const float* __restrict__ bias,
                                                    const ushort* __restrict__ dtr,
                                                    const float* __restrict__ dt_bias,
                                                    const float* __restrict__ A_log,
                                                    ushort* __restrict__ xbcc,
                                                    ushort* __restrict__ xT,
                                                    ushort* __restrict__ Bt,
                                                    float* __restrict__ dtp,
                                                    float* __restrict__ dacs) {
    __shared__ ushort xin[35][136];
    __shared__ ushort yL[32][132];
    const int stile = blockIdx.x, slot = blockIdx.y, bc = blockIdx.z;
    const int tid = threadIdx.x;

    if (slot == 34) {
        // ---- prep path: 4 waves, each one (bi,cc,h) unit ----
        const int lane = tid & 63, wave = tid >> 6;
        const int g = (bc * 8 + stile) * 4 + wave;      // 0..511
        const int h = g & 31, cc = (g >> 5) & 7, bi = g >> 8;
        const float Aa = -__expf(A_log[h]);
        const float bsh = dt_bias[h];
        float v[4], cs[4];
        float run = 0.f;
#pragma unroll
        for (int j = 0; j < 4; j++) {
            int pos = cc * 256 + lane * 4 + j;
            float raw = bf2f(dtr[((long)(bi * 2048 + pos)) * 32 + h]) + bsh;
            float sp = (raw > 20.f) ? raw : log1pf(__expf(raw));
            float d = fminf(fmaxf(sp, 0.001f), 0.1f);
            v[j] = d;
            run += d * Aa;
            cs[j] = run;
        }
        float tot = run, pre = run;
        for (int off = 1; off < 64; off <<= 1) {
            float u = __shfl_up(pre, off, 64);
            if (lane >= off) pre += u;
        }
        float excl = pre - tot;
        const long base = ((long)(bi * 32 + h)) * 2048 + cc * 256 + lane * 4;
#pragma unroll
        for (int j = 0; j < 4; j++) { dtp[base + j] = v[j]; dacs[base + j] = excl + cs[j]; }
        return;
    }

    // ---- conv path ----
    const int cc = bc & 7;
    const long tbase = (long)bc * 256 + stile * 32;
    const int c0 = slot * 128;
    const bool head = (cc == 0 && stile == 0);

#pragma unroll
    for (int i = 0; i < 3; i++) {
        int u = tid + i * 256;
        if (u < 560) {
            int r = u >> 4, seg = u & 15;
            s16x8 v;
            if (head && r < 3) {
#pragma unroll
                for (int j = 0; j < 8; j++) v[j] = 0;
            } else {
                v = *(const s16x8*)&xbc[(tbase - 3 + r) * 4352 + c0 + seg * 8];
            }
            *(s16x8*)&xin[r][seg * 8] = v;
        }
    }
    __syncthreads();

    const int s_loc = tid >> 3, p0 = (tid & 7) * 16;
    ushort yo[16];
#pragma unroll
    for (int j = 0; j < 16; j++) {
        int c = p0 + j;
        float a = bias[c0 + c];
#pragma unroll
        for (int k = 0; k < 4; k++)
            a += bf2f(xin[s_loc + k][c]) * w[(c0 + c) * 4 + k];
        float yv = a / (1.f + __expf(-a));
        ushort ub = f2bf(yv);
        yo[j] = ub;
        yL[s_loc][c] = ub;
    }
    *(s16x8*)&xbcc[(tbase + s_loc) * 4352 + c0 + p0] = *(const s16x8*)&yo[0];
    *(s16x8*)&xbcc[(tbase + s_loc) * 4352 + c0 + p0 + 8] = *(const s16x8*)&yo[8];
    __syncthreads();

    if (slot < 33) {
        const int p = tid >> 1, s0 = (tid & 1) * 16;
        ushort o[16];
#pragma unroll
        for (int j = 0; j < 16; j++) o[j] = yL[s0 + j][p];
        ushort* dst = (slot < 32)
            ? (xT + ((long)(bc * 32 + slot) * 128 + p) * 256 + stile * 32 + s0)
            : (Bt + ((long)bc * 128 + p) * 256 + stile * 32 + s0);
        *(s16x8*)&dst[0] = *(const s16x8*)&o[0];
        *(s16x8*)&dst[8] = *(const s16x8*)&o[8];
    }
}

// ---------------- merged: per-chunk end states (bid<512) + CB (bid>=512) ---
__global__ __launch_bounds__(256) void states_cb_k(const ushort* __restrict__ xT,
                                                   const ushort* __restrict__ Bt,
                                                   const float* __restrict__ dtp,
                                                   const float* __restrict__ dacs,
                                                   const ushort* __restrict__ xbcc,
                                                   float* __restrict__ states,
                                                   float* __restrict__ CB) {
    __shared__ float wl[256];
    const int bid = blockIdx.x;
    const int tid = threadIdx.x, lane = tid & 63, wave = tid >> 6;
    const int wm = wave >> 1, wn = wave & 1;
    f32x4 zero = { 0.f, 0.f, 0.f, 0.f };
    f32x4 acc[4][4];
#pragma unroll
    for (int i = 0; i < 4; i++)
#pragma unroll
        for (int j = 0; j < 4; j++) acc[i][j] = zero;

    if (bid < 512) {
        // ---- states path ----
        const int h = bid & 31, cc = (bid >> 5) & 7, bi = bid >> 8;
        const int bc = bi * 8 + cc;
        const long dbase = ((long)(bi * 32 + h)) * 2048 + cc * 256;
        {
            float last = dacs[dbase + 255];
            wl[tid] = __expf(last - dacs[dbase + tid]) * dtp[dbase + tid];
        }
        __syncthreads();

        const ushort* xrow = xT + (((long)bc * 32 + h) * 128) * 256;
        const ushort* brow = Bt + ((long)bc * 128) * 256;

        for (int sb = 0; sb < 8; ++sb) {
            const int soff = sb * 32 + (lane >> 4) * 8;
            s16x8 a[4], b[4];
#pragma unroll
            for (int mi = 0; mi < 4; mi++) {
                int p = wm * 64 + mi * 16 + (lane & 15);
                s16x8 raw = *(const s16x8*)&xrow[(long)p * 256 + soff];
#pragma unroll
                for (int j = 0; j < 8; j++)
                    a[mi][j] = (short)f2bf(bf2f((ushort)raw[j]) * wl[soff + j]);
            }
#pragma unroll
            for (int ni = 0; ni < 4; ni++) {
                int n = wn * 64 + ni * 16 + (lane & 15);
                b[ni] = *(const s16x8*)&brow[(long)n * 256 + soff];
            }
#pragma unroll
            for (int mi = 0; mi < 4; mi++)
#pragma unroll
                for (int ni = 0; ni < 4; ni++)
                    acc[mi][ni] = __builtin_amdgcn_mfma_f32_16x16x32_bf16(a[mi], b[ni], acc[mi][ni], 0, 0, 0);
        }

        float* out = states + (((long)bc * 32 + h) * 128) * 128;
#pragma unroll
        for (int mi = 0; mi < 4; mi++)
#pragma unroll
            for (int ni = 0; ni < 4; ni++)
#pragma unroll
                for (int r = 0; r < 4; r++) {
                    int p = wm * 64 + mi * 16 + (lane >> 4) * 4 + r;
                    int n = wn * 64 + ni * 16 + (lane & 15);
                    out[(long)p * 128 + n] = acc[mi][ni][r];
                }
    } else {
        // ---- CB path ----
        const int b2 = bid - 512;                  // 0..63
        const int sq = b2 & 1, lq = (b2 >> 1) & 1, bc = b2 >> 2;
        const long tbase = (long)bc * 256;

        for (int kst = 0; kst < 4; ++kst) {
            const int koff = kst * 32 + (lane >> 4) * 8;
            s16x8 a[4], b[4];
#pragma unroll
            for (int mi = 0; mi < 4; mi++) {
                int l = lq * 128 + wm * 64 + mi * 16 + (lane & 15);
                a[mi] = *(const s16x8*)&xbcc[(tbase + l) * 4352 + 4224 + koff];
            }
#pragma unroll
            for (int ni = 0; ni < 4; ni++) {
                int s = sq * 128 + wn * 64 + ni * 16 + (lane & 15);
                b[ni] = *(const s16x8*)&xbcc[(tbase + s) * 4352 + 4096 + koff];
            }
#pragma unroll
            for (int mi = 0; mi < 4; mi++)
#pragma unroll
                for (int ni = 0; ni < 4; ni++)
                    acc[mi][ni] = __builtin_amdgcn_mfma_f32_16x16x32_bf16(a[mi], b[ni], acc[mi][ni], 0, 0, 0);
        }

        float* out = CB + (long)bc * 65536;
#pragma unroll
        for (int mi = 0; mi < 4; mi++)
#pragma unroll
            for (int ni = 0; ni < 4; ni++)
#pragma unroll
                for (int r = 0; r < 4; r++) {
                    int l = lq * 128 + wm * 64 + mi * 16 + (lane >> 4) * 4 + r;
                    int s = sq * 128 + wn * 64 + ni * 16 + (lane & 15);
                    out[(long)l * 256 + s] = acc[mi][ni][r];
                }
    }
}

// ---------------- fused intra+inter scan via MFMA (single bf16 write) ------
__global__ __launch_bounds__(256) void scan_mfma_k(const ushort* __restrict__ xT,
                                                   const float* __restrict__ CB,
                                                   const float* __restrict__ dtp,
                                                   const float* __restrict__ dacs,
                                                   const ushort* __restrict__ xbcc,
                                                   const float* __restrict__ st,
                                                   ushort* __restrict__ yh) {
    const int bx = blockIdx.x;
    const int ltile = bx & 1, h = (bx >> 1) & 31, cc = (bx >> 6) & 7, bi = bx >> 9;
    const int tid = threadIdx.x, lane = tid & 63, wave = tid >> 6;
    const int wm = wave >> 1, wn = wave & 1;

    __shared__ float dA_s[256];
    __shared__ float F_s[256];

    const long dbase = ((long)(bi * 32 + h)) * 2048 + cc * 256;
    {
        float a = dacs[dbase + tid];
        float r = dacs[dbase + (tid | 31)];
        dA_s[tid] = a;
        F_s[tid] = __expf(r - a) * dtp[dbase + tid];
    }
    __syncthreads();

    int lch[4];
    float dAl[4];
#pragma unroll
    for (int mi = 0; mi < 4; mi++) {
        lch[mi] = ltile * 128 + wm * 64 + mi * 16 + (lane & 15);
        dAl[mi] = dA_s[lch[mi]];
    }

    f32x4 zero = { 0.f, 0.f, 0.f, 0.f };
    f32x4 acc[4][4];
#pragma unroll
    for (int i = 0; i < 4; i++)
#pragma unroll
        for (int j = 0; j < 4; j++) acc[i][j] = zero;

    const long tbase = (long)bi * 2048 + cc * 256;
    const long cbbase = ((long)(bi * 8 + cc)) * 65536;
    const ushort* xrow = xT + (((long)(bi * 8 + cc) * 32 + h) * 128) * 256;
    const int nsb = ltile * 4 + 4;

    for (int sb = 0; sb < nsb; ++sb) {
        const int soff = sb * 32 + (lane >> 4) * 8;
        s16x8 bf[4];
#pragma unroll
        for (int ni = 0; ni < 4; ni++) {
            int p = wn * 64 + ni * 16 + (lane & 15);
            bf[ni] = *(const s16x8*)&xrow[(long)p * 256 + soff];
        }
        const float Rsb = dA_s[sb * 32 + 31];
        const int s0 = soff;
#pragma unroll
        for (int mi = 0; mi < 4; mi++) {
            const int lb = lch[mi] >> 5;
            if (sb > lb) continue;
            const float* cbrow = CB + cbbase + (long)lch[mi] * 256 + s0;
            float4 c0 = *(const float4*)cbrow;
            float4 c1 = *(const float4*)(cbrow + 4);
            float E = __expf(dAl[mi] - Rsb);
            float m[8];
            m[0] = c0.x * E * F_s[s0 + 0]; m[1] = c0.y * E * F_s[s0 + 1];
            m[2] = c0.z * E * F_s[s0 + 2]; m[3] = c0.w * E * F_s[s0 + 3];
            m[4] = c1.x * E * F_s[s0 + 4]; m[5] = c1.y * E * F_s[s0 + 5];
            m[6] = c1.z * E * F_s[s0 + 6]; m[7] = c1.w * E * F_s[s0 + 7];
            if (sb == lb) {
#pragma unroll
                for (int j = 0; j < 8; j++)
                    if (s0 + j > lch[mi]) m[j] = 0.f;
            }
            s16x8 a;
#pragma unroll
            for (int j = 0; j < 8; j++) a[j] = (short)f2bf(m[j]);
#pragma unroll
            for (int ni = 0; ni < 4; ni++)
                acc[mi][ni] = __builtin_amdgcn_mfma_f32_16x16x32_bf16(a, bf[ni], acc[mi][ni], 0, 0, 0);
        }
    }

    const float* sbase = st + (((long)(bi * 8 + cc) * 32 + h) * 128) * 128;
    float eAr[4];
#pragma unroll
    for (int mi = 0; mi < 4; mi++) eAr[mi] = __expf(dAl[mi]);
    for (int kk = 0; kk < 4; ++kk) {
        const int koff = kk * 32 + (lane >> 4) * 8;
        s16x8 a[4], b[4];
#pragma unroll
        for (int mi = 0; mi < 4; mi++) {
            s16x8 raw = *(const s16x8*)&xbcc[(tbase + lch[mi]) * 4352 + 4224 + koff];
#pragma unroll
            for (int j = 0; j < 8; j++)
                a[mi][j] = (short)f2bf(bf2f((ushort)raw[j]) * eAr[mi]);
        }
#pragma unroll
        for (int ni = 0; ni < 4; ni++) {
            int p = wn * 64 + ni * 16 + (lane & 15);
            const float* pr = sbase + (long)p * 128 + koff;
            float4 v0 = *(const float4*)pr;
            float4 v1 = *(const float4*)(pr + 4);
            b[ni][0] = (short)f2bf(v0.x); b[ni][1] = (short)f2bf(v0.y);
            b[ni][2] = (short)f2bf(v0.z); b[ni][3] = (short)f2bf(v0.w);
            b[ni][4] = (short)f2bf(v1.x); b[ni][5] = (short)f2bf(v1.y);
            b[ni][6] = (short)f2bf(v1.z); b[ni][7] = (short)f2bf(v1.w);
        }
#pragma unroll
        for (int mi = 0; mi < 4; mi++)
#pragma unroll
            for (int ni = 0; ni < 4; ni++)
                acc[mi][ni] = __builtin_amdgcn_mfma_f32_16x16x32_bf16(a[mi], b[ni], acc[mi][ni], 0, 0, 0);
    }

    const long crow = tbase + ltile * 128 + wm * 64 + ((lane >> 4) << 2);
    const int ccol = h * 128 + wn * 64 + (lane & 15);
#pragma unroll
    for (int mi = 0; mi < 4; mi++)
#pragma unroll
        for (int ni = 0; ni < 4; ni++)
#pragma unroll
            for (int r = 0; r < 4; r++)
                yh[(crow + mi * 16 + r) * 4096 + ccol + ni * 16] = f2bf(acc[mi][ni][r]);
}

// ---------------- chunk recurrence: states -> prev_states (in place) ----------------
__global__ void rec_k(float* __restrict__ states, const float* __restrict__ dacs) {
    const int i = blockIdx.x * 256 + threadIdx.x;
    const int n = i & 127, p = (i >> 7) & 127, h = (i >> 14) & 31, bi = i >> 19;
    const long dbase = ((long)(bi * 32 + h)) * 2048;
    float run = 0.f;
    for (int cc = 0; cc < 8; cc++) {
        const long off = ((((long)(bi * 8 + cc)) * 32 + h) * 128 + p) * 128 + n;
        float st = states[off];
        states[off] = run;
        float dec = dacs[dbase + cc * 256 + 255];
        run = run * __expf(dec) + st;
    }
}

// ---------------- gate (silu(z)) + D*x + RMSNorm -> bf16 ----------------
__global__ __launch_bounds__(256) void gate_rms_k(const ushort* __restrict__ yh, const ushort* __restrict__ zbuf,
                                                  const ushort* __restrict__ xbcc, const float* __restrict__ Dv,
                                                  const float* __restrict__ norm_w, ushort* __restrict__ yb) {
    const int t = blockIdx.x, tid = threadIdx.x;
    const ushort* yr = &yh[(long)t * 4096];
    const ushort* zr = &zbuf[(long)t * 4096];
    const ushort* xr = &xbcc[(long)t * 4352];
    float g[16];
    float ss = 0.f;
#pragma unroll
    for (int j = 0; j < 16; j++) {
        int i = j * 256 + tid;
        float z = bf2f(zr[i]);
        float yv = bf2f(yr[i]) + Dv[i >> 7] * bf2f(xr[i]);
        float gv = yv * (z / (1.f + __expf(-z)));
        g[j] = gv;
        ss += gv * gv;
    }
#pragma unroll
    for (int off = 32; off > 0; off >>= 1) ss += __shfl_xor(ss, off, 64);
    __shared__ float red[4];
    if ((tid & 63) == 0) red[tid >> 6] = ss;
    __syncthreads();
    float tot = red[0] + red[1] + red[2] + red[3];
    float sc = rsqrtf(tot * (1.f / 4096.f) + 1e-6f);
#pragma unroll
    for (int j = 0; j < 16; j++) {
        int i = j * 256 + tid;
        yb[(long)t * 4096 + i] = f2bf(g[j] * sc * norm_w[i]);
    }
}

// ---------------------------------------------------------------------------
extern "C" void kernel_launch(void* const* d_in, const int* in_sizes, int n_in,
                              void* d_out, int out_size, void* d_ws, size_t ws_size,
                              hipStream_t stream) {
    const float* x       = (const float*)d_in[0];
    const float* W_in    = (const float*)d_in[1];
    const float* conv_w  = (const float*)d_in[2];
    const float* conv_b  = (const float*)d_in[3];
    const float* dt_bias = (const float*)d_in[4];
    const float* A_log   = (const float*)d_in[5];
    const float* Dv      = (const float*)d_in[6];
    const float* norm_w  = (const float*)d_in[7];
    const float* W_out   = (const float*)d_in[8];

    char* w8 = (char*)d_ws;
    ushort* xb    = (ushort*)(w8 + 0L);
    ushort* xT    = (ushort*)(w8 + 0L);            // alias (xb dead after GEMM1)
    ushort* yb    = (ushort*)(w8 + 0L);            // alias (xT dead before gate)
    ushort* woutb = (ushort*)(w8 + 33554432L);
    ushort* Bt    = (ushort*)(w8 + 50331648L);
    ushort* zbuf  = (ushort*)(w8 + 52428800L);
    ushort* xbc   = (ushort*)(w8 + 85983232L);
    ushort* dtr   = (ushort*)(w8 + 121634816L);
    ushort* xbcc  = (ushort*)(w8 + 121896960L);
    float*  dtp   = (float*)(w8 + 157548544L);
    float*  dacs  = (float*)(w8 + 158072832L);
    float*  cb    = (float*)(w8 + 158597120L);
    ushort* yh    = (ushort*)(w8 + 162791424L);    // bf16 scan output
    ushort* winb  = (ushort*)(w8 + 162791424L);    // alias (dead before yh written)
    float*  st    = (float*)(w8 + 229900288L);

    cast_all_k<<<34048, 256, 0, stream>>>((const float4*)x, (const float4*)W_out,
                                          (const float4*)W_in, xb, woutb, winb);
    gemm1_k<<<736, 512, 0, stream>>>(xb, winb, zbuf, xbc, dtr);
    convx_prep_k<<<dim3(8, 35, 16), 256, 0, stream>>>(xbc, conv_w, conv_b, dtr,
                                                      dt_bias, A_log, xbcc, xT, Bt,
                                                      dtp, dacs);
    states_cb_k<<<576, 256, 0, stream>>>(xT, Bt, dtp, dacs, xbcc, st, cb);
    rec_k<<<4096, 256, 0, stream>>>(st, dacs);
    scan_mfma_k<<<1024, 256, 0, stream>>>(xT, cb, dtp, dacs, xbcc, st, yh);
    gate_rms_k<<<4096, 256, 0, stream>>>(yh, zbuf, xbcc, Dv, norm_w, yb);
    gemm2_k<<<512, 256, 0, stream>>>(yb, woutb, (float*)d_out);
}